// Round 2
// baseline (733.294 us; speedup 1.0000x reference)
//
#include <hip/hip_runtime.h>
#include <stdint.h>

#define N_NODES 40000
#define N_EDGES 640000
#define HID 128
#define NGRAPH 64
#define NCLASS 10

// ---------------- degree histogram over dst ----------------
__global__ void k_degree(const int* __restrict__ dst, int* __restrict__ cnt) {
    int e = blockIdx.x * blockDim.x + threadIdx.x;
    if (e < N_EDGES) atomicAdd(&cnt[dst[e]], 1);
}

// ---------------- dinv + per-graph node counts ----------------
__global__ void k_dinv(const int* __restrict__ cnt, float* __restrict__ dinv,
                       const int* __restrict__ batch, int* __restrict__ gcnt) {
    int i = blockIdx.x * blockDim.x + threadIdx.x;
    if (i < N_NODES) {
        dinv[i] = rsqrtf((float)(cnt[i] + 1));   // +1 self-loop; deg >= 1 always
        atomicAdd(&gcnt[batch[i]], 1);
    }
}

// ---------------- exclusive scan of cnt -> row_ptr (single block, 1024 thr) ----------------
__global__ void k_scan(const int* __restrict__ cnt, int* __restrict__ row_ptr) {
    __shared__ int wsum[16];
    int t = threadIdx.x;
    int lane = t & 63, wv = t >> 6;
    int carry = 0;
    for (int base = 0; base < N_NODES; base += 1024) {
        int idx = base + t;
        int v = (idx < N_NODES) ? cnt[idx] : 0;
        int x = v;
        #pragma unroll
        for (int d = 1; d < 64; d <<= 1) {
            int y = __shfl_up(x, d, 64);
            if (lane >= d) x += y;
        }
        if (lane == 63) wsum[wv] = x;
        __syncthreads();
        int off = 0, tot = 0;
        #pragma unroll
        for (int w = 0; w < 16; ++w) {
            int s = wsum[w];
            if (w < wv) off += s;
            tot += s;
        }
        if (idx < N_NODES) row_ptr[idx] = carry + off + (x - v);
        carry += tot;
        __syncthreads();
    }
    if (t == 0) row_ptr[N_NODES] = carry;
}

// ---------------- CSR fill (grouped by dst) + per-edge weight ----------------
__global__ void k_fill(const int* __restrict__ srcs, const int* __restrict__ dsts,
                       const int* __restrict__ row_ptr, int* __restrict__ cursor,
                       const float* __restrict__ dinv,
                       int* __restrict__ csr_src, float* __restrict__ csr_w) {
    int e = blockIdx.x * blockDim.x + threadIdx.x;
    if (e < N_EDGES) {
        int s = srcs[e], d = dsts[e];
        int p = row_ptr[d] + atomicAdd(&cursor[d], 1);
        csr_src[p] = s;
        csr_w[p] = dinv[s] * dinv[d];
    }
}

// ---------------- fp32 GEMM: Out[M,128] = A[M,128] @ W[128,128], W in LDS ----------------
__launch_bounds__(256)
__global__ void k_gemm(const float* __restrict__ A, const float* __restrict__ W,
                       float* __restrict__ Out) {
    __shared__ float wl[HID * HID];   // 64 KB
    int t = threadIdx.x;
    const float4* w4 = (const float4*)W;
    float4* wl4 = (float4*)wl;
    for (int i = t; i < HID * HID / 4; i += 256) wl4[i] = w4[i];
    __syncthreads();
    int lane = t & 63, wv = t >> 6;
    int nw = gridDim.x * 4;
    for (int row = blockIdx.x * 4 + wv; row < N_NODES; row += nw) {
        const float* ar = A + (size_t)row * HID;
        float acc0 = 0.f, acc1 = 0.f;
        #pragma unroll 8
        for (int k = 0; k < HID; ++k) {
            float av = ar[k];                      // wave-uniform broadcast load
            acc0 += av * wl[k * HID + lane];       // 2 lanes/bank: free
            acc1 += av * wl[k * HID + lane + 64];
        }
        Out[(size_t)row * HID + lane] = acc0;
        Out[(size_t)row * HID + lane + 64] = acc1;
    }
}

// ---------------- aggregation: out[i] = relu(dinv_i^2*xw[i] + sum_e w_e*xw[src_e] + b)
// one wave per node, lane handles feats (2*lane, 2*lane+1) as float2.
// mode 0: write fp32 rows; mode 1: atomicAdd relu'd row into pool[batch[i]]
__launch_bounds__(256, 8)
__global__ void k_agg(const float* __restrict__ in, const float* __restrict__ dinv,
                      const int* __restrict__ row_ptr, const int* __restrict__ csr_src,
                      const float* __restrict__ csr_w, const float* __restrict__ bias,
                      float* __restrict__ out, float* __restrict__ pool,
                      const int* __restrict__ batch, int mode) {
    int wid = (blockIdx.x * blockDim.x + threadIdx.x) >> 6;   // one wave per node
    int lane = threadIdx.x & 63;
    if (wid >= N_NODES) return;
    int i = wid;
    float di = dinv[i];
    float2 self = *(const float2*)(in + (size_t)i * HID + lane * 2);
    float a0 = self.x * di * di;
    float a1 = self.y * di * di;

    int e = row_ptr[i], e1 = row_ptr[i + 1];
    for (; e + 4 <= e1; e += 4) {
        int s0 = csr_src[e], s1 = csr_src[e + 1], s2 = csr_src[e + 2], s3 = csr_src[e + 3];
        float w0 = csr_w[e], w1 = csr_w[e + 1], w2 = csr_w[e + 2], w3 = csr_w[e + 3];
        float2 p0 = *(const float2*)(in + (size_t)s0 * HID + lane * 2);
        float2 p1 = *(const float2*)(in + (size_t)s1 * HID + lane * 2);
        float2 p2 = *(const float2*)(in + (size_t)s2 * HID + lane * 2);
        float2 p3 = *(const float2*)(in + (size_t)s3 * HID + lane * 2);
        a0 += w0 * p0.x;  a1 += w0 * p0.y;
        a0 += w1 * p1.x;  a1 += w1 * p1.y;
        a0 += w2 * p2.x;  a1 += w2 * p2.y;
        a0 += w3 * p3.x;  a1 += w3 * p3.y;
    }
    for (; e < e1; ++e) {
        int s = csr_src[e];
        float w = csr_w[e];
        float2 p = *(const float2*)(in + (size_t)s * HID + lane * 2);
        a0 += w * p.x;
        a1 += w * p.y;
    }
    a0 = fmaxf(a0 + bias[lane * 2], 0.f);
    a1 = fmaxf(a1 + bias[lane * 2 + 1], 0.f);
    if (mode == 0) {
        float2 o = {a0, a1};
        *(float2*)(out + (size_t)i * HID + lane * 2) = o;
    } else {
        int g = batch[i];
        atomicAdd(&pool[g * HID + lane * 2], a0);
        atomicAdd(&pool[g * HID + lane * 2 + 1], a1);
    }
}

// ---------------- final: logits[g,k] = (pool[g,:]/cnt) @ lin_w + lin_b ----------------
__global__ void k_final(const float* __restrict__ pool, const int* __restrict__ gcnt,
                        const float* __restrict__ lin_w, const float* __restrict__ lin_b,
                        float* __restrict__ outp) {
    __shared__ float sh[HID];
    int g = blockIdx.x;
    int t = threadIdx.x;   // 128 threads
    float c = fmaxf((float)gcnt[g], 1.f);
    sh[t] = pool[g * HID + t] / c;
    __syncthreads();
    if (t < NCLASS) {
        float acc = lin_b[t];
        for (int f = 0; f < HID; ++f)
            acc += sh[f] * lin_w[f * NCLASS + t];
        outp[g * NCLASS + t] = acc;
    }
}

extern "C" void kernel_launch(void* const* d_in, const int* in_sizes, int n_in,
                              void* d_out, int out_size, void* d_ws, size_t ws_size,
                              hipStream_t stream) {
    const float* x    = (const float*)d_in[0];
    const int* eidx   = (const int*)d_in[1];
    const int* batch  = (const int*)d_in[2];
    const float* W1   = (const float*)d_in[3];
    const float* b1   = (const float*)d_in[4];
    const float* W2   = (const float*)d_in[5];
    const float* b2   = (const float*)d_in[6];
    const float* lw   = (const float*)d_in[7];
    const float* lb   = (const float*)d_in[8];
    float* out = (float*)d_out;

    char* ws = (char*)d_ws;
    int*   cnt     = (int*)(ws + 0);                 // 160000 B
    int*   cursor  = (int*)(ws + 160000);            // 160000 B
    int*   gcnt    = (int*)(ws + 320000);            // 256 B
    float* pool    = (float*)(ws + 320256);          // 32768 B  (zero region ends 353024)
    int*   row_ptr = (int*)(ws + 353024);            // 160016 B (pad to 513088)
    float* dinv    = (float*)(ws + 513088);          // 160000 B
    int*   csr_src = (int*)(ws + 673088);            // 2560000 B
    float* csr_w   = (float*)(ws + 3233088);         // 2560000 B
    float* bufA    = (float*)(ws + 5793088);         // 20480000 B
    float* bufB    = (float*)(ws + 26273088);        // 20480000 B (total ~46.8 MB)

    const int* src = eidx;             // edge_index[0]
    const int* dst = eidx + N_EDGES;   // edge_index[1]

    hipMemsetAsync(d_ws, 0, 353024, stream);
    k_degree<<<2500, 256, 0, stream>>>(dst, cnt);
    k_dinv<<<157, 256, 0, stream>>>(cnt, dinv, batch, gcnt);
    k_scan<<<1, 1024, 0, stream>>>(cnt, row_ptr);
    k_fill<<<2500, 256, 0, stream>>>(src, dst, row_ptr, cursor, dinv, csr_src, csr_w);

    k_gemm<<<512, 256, 0, stream>>>(x, W1, bufA);                       // xw1
    k_agg<<<10000, 256, 0, stream>>>(bufA, dinv, row_ptr, csr_src, csr_w,
                                     b1, bufB, nullptr, batch, 0);      // h1
    k_gemm<<<512, 256, 0, stream>>>(bufB, W2, bufA);                    // h1@W2
    k_agg<<<10000, 256, 0, stream>>>(bufA, dinv, row_ptr, csr_src, csr_w,
                                     b2, nullptr, pool, batch, 1);      // h2 -> pooled sums
    k_final<<<64, 128, 0, stream>>>(pool, gcnt, lw, lb, out);
}

// Round 3
// 500.961 us; speedup vs baseline: 1.4638x; 1.4638x over previous
//
#include <hip/hip_runtime.h>
#include <stdint.h>

#define N_NODES 40000
#define N_EDGES 640000
#define HID 128
#define NGRAPH 64
#define NCLASS 10

// ---------------- degree histogram over dst ----------------
__global__ void k_degree(const int* __restrict__ dst, int* __restrict__ cnt) {
    int e = blockIdx.x * blockDim.x + threadIdx.x;
    if (e < N_EDGES) atomicAdd(&cnt[dst[e]], 1);
}

// ---------------- dinv (no more gcnt atomics — graph counts come from sorted batch) ----
__global__ void k_dinv(const int* __restrict__ cnt, float* __restrict__ dinv) {
    int i = blockIdx.x * blockDim.x + threadIdx.x;
    if (i < N_NODES) {
        dinv[i] = rsqrtf((float)(cnt[i] + 1));   // +1 self-loop; deg >= 1 always
    }
}

// ---------------- exclusive scan of cnt -> row_ptr (single block, 1024 thr) ----------------
__global__ void k_scan(const int* __restrict__ cnt, int* __restrict__ row_ptr) {
    __shared__ int wsum[16];
    int t = threadIdx.x;
    int lane = t & 63, wv = t >> 6;
    int carry = 0;
    for (int base = 0; base < N_NODES; base += 1024) {
        int idx = base + t;
        int v = (idx < N_NODES) ? cnt[idx] : 0;
        int x = v;
        #pragma unroll
        for (int d = 1; d < 64; d <<= 1) {
            int y = __shfl_up(x, d, 64);
            if (lane >= d) x += y;
        }
        if (lane == 63) wsum[wv] = x;
        __syncthreads();
        int off = 0, tot = 0;
        #pragma unroll
        for (int w = 0; w < 16; ++w) {
            int s = wsum[w];
            if (w < wv) off += s;
            tot += s;
        }
        if (idx < N_NODES) row_ptr[idx] = carry + off + (x - v);
        carry += tot;
        __syncthreads();
    }
    if (t == 0) row_ptr[N_NODES] = carry;
}

// ---------------- CSR fill (grouped by dst) + per-edge weight ----------------
__global__ void k_fill(const int* __restrict__ srcs, const int* __restrict__ dsts,
                       const int* __restrict__ row_ptr, int* __restrict__ cursor,
                       const float* __restrict__ dinv,
                       int* __restrict__ csr_src, float* __restrict__ csr_w) {
    int e = blockIdx.x * blockDim.x + threadIdx.x;
    if (e < N_EDGES) {
        int s = srcs[e], d = dsts[e];
        int p = row_ptr[d] + atomicAdd(&cursor[d], 1);
        csr_src[p] = s;
        csr_w[p] = dinv[s] * dinv[d];
    }
}

// ---------------- fp32 GEMM: Out[M,128] = A[M,128] @ W[128,128], W in LDS ----------------
__launch_bounds__(256)
__global__ void k_gemm(const float* __restrict__ A, const float* __restrict__ W,
                       float* __restrict__ Out) {
    __shared__ float wl[HID * HID];   // 64 KB
    int t = threadIdx.x;
    const float4* w4 = (const float4*)W;
    float4* wl4 = (float4*)wl;
    for (int i = t; i < HID * HID / 4; i += 256) wl4[i] = w4[i];
    __syncthreads();
    int lane = t & 63, wv = t >> 6;
    int nw = gridDim.x * 4;
    for (int row = blockIdx.x * 4 + wv; row < N_NODES; row += nw) {
        const float* ar = A + (size_t)row * HID;
        float acc0 = 0.f, acc1 = 0.f;
        #pragma unroll 8
        for (int k = 0; k < HID; ++k) {
            float av = ar[k];                      // wave-uniform broadcast load
            acc0 += av * wl[k * HID + lane];       // 2 lanes/bank: free
            acc1 += av * wl[k * HID + lane + 64];
        }
        Out[(size_t)row * HID + lane] = acc0;
        Out[(size_t)row * HID + lane + 64] = acc1;
    }
}

// ---------------- aggregation: out[i] = relu(dinv_i^2*xw[i] + sum_e w_e*xw[src_e] + b)
// one wave per node, lane handles feats (2*lane, 2*lane+1) as float2.
__launch_bounds__(256, 8)
__global__ void k_agg(const float* __restrict__ in, const float* __restrict__ dinv,
                      const int* __restrict__ row_ptr, const int* __restrict__ csr_src,
                      const float* __restrict__ csr_w, const float* __restrict__ bias,
                      float* __restrict__ out) {
    int wid = (blockIdx.x * blockDim.x + threadIdx.x) >> 6;   // one wave per node
    int lane = threadIdx.x & 63;
    if (wid >= N_NODES) return;
    int i = wid;
    float di = dinv[i];
    float2 self = *(const float2*)(in + (size_t)i * HID + lane * 2);
    float a0 = self.x * di * di;
    float a1 = self.y * di * di;

    int e = row_ptr[i], e1 = row_ptr[i + 1];
    for (; e + 4 <= e1; e += 4) {
        int s0 = csr_src[e], s1 = csr_src[e + 1], s2 = csr_src[e + 2], s3 = csr_src[e + 3];
        float w0 = csr_w[e], w1 = csr_w[e + 1], w2 = csr_w[e + 2], w3 = csr_w[e + 3];
        float2 p0 = *(const float2*)(in + (size_t)s0 * HID + lane * 2);
        float2 p1 = *(const float2*)(in + (size_t)s1 * HID + lane * 2);
        float2 p2 = *(const float2*)(in + (size_t)s2 * HID + lane * 2);
        float2 p3 = *(const float2*)(in + (size_t)s3 * HID + lane * 2);
        a0 += w0 * p0.x;  a1 += w0 * p0.y;
        a0 += w1 * p1.x;  a1 += w1 * p1.y;
        a0 += w2 * p2.x;  a1 += w2 * p2.y;
        a0 += w3 * p3.x;  a1 += w3 * p3.y;
    }
    for (; e < e1; ++e) {
        int s = csr_src[e];
        float w = csr_w[e];
        float2 p = *(const float2*)(in + (size_t)s * HID + lane * 2);
        a0 += w * p.x;
        a1 += w * p.y;
    }
    a0 = fmaxf(a0 + bias[lane * 2], 0.f);
    a1 = fmaxf(a1 + bias[lane * 2 + 1], 0.f);
    float2 o = {a0, a1};
    *(float2*)(out + (size_t)i * HID + lane * 2) = o;
}

// ---------------- pool + linear: one block per graph, batch sorted -> contiguous range ----
__launch_bounds__(128)
__global__ void k_pool(const float* __restrict__ h, const int* __restrict__ batch,
                       const float* __restrict__ lin_w, const float* __restrict__ lin_b,
                       float* __restrict__ outp) {
    __shared__ float sh[HID];
    int g = blockIdx.x;
    int t = threadIdx.x;   // 128 threads, thread = feature
    // binary search: lo = first i with batch[i] >= g ; hi = first i with batch[i] >= g+1
    int lo = 0, n = N_NODES;
    while (n > 0) { int half = n >> 1; int mid = lo + half;
        if (batch[mid] < g) { lo = mid + 1; n -= half + 1; } else n = half; }
    int hi = lo, n2 = N_NODES - lo;
    while (n2 > 0) { int half = n2 >> 1; int mid = hi + half;
        if (batch[mid] < g + 1) { hi = mid + 1; n2 -= half + 1; } else n2 = half; }
    float acc0 = 0.f, acc1 = 0.f, acc2 = 0.f, acc3 = 0.f;
    int r = lo;
    for (; r + 4 <= hi; r += 4) {
        acc0 += h[(size_t)r * HID + t];
        acc1 += h[(size_t)(r + 1) * HID + t];
        acc2 += h[(size_t)(r + 2) * HID + t];
        acc3 += h[(size_t)(r + 3) * HID + t];
    }
    for (; r < hi; ++r) acc0 += h[(size_t)r * HID + t];
    float c = fmaxf((float)(hi - lo), 1.f);
    sh[t] = (acc0 + acc1 + acc2 + acc3) / c;
    __syncthreads();
    if (t < NCLASS) {
        float acc = lin_b[t];
        #pragma unroll 8
        for (int f = 0; f < HID; ++f)
            acc += sh[f] * lin_w[f * NCLASS + t];
        outp[g * NCLASS + t] = acc;
    }
}

extern "C" void kernel_launch(void* const* d_in, const int* in_sizes, int n_in,
                              void* d_out, int out_size, void* d_ws, size_t ws_size,
                              hipStream_t stream) {
    const float* x    = (const float*)d_in[0];
    const int* eidx   = (const int*)d_in[1];
    const int* batch  = (const int*)d_in[2];
    const float* W1   = (const float*)d_in[3];
    const float* b1   = (const float*)d_in[4];
    const float* W2   = (const float*)d_in[5];
    const float* b2   = (const float*)d_in[6];
    const float* lw   = (const float*)d_in[7];
    const float* lb   = (const float*)d_in[8];
    float* out = (float*)d_out;

    char* ws = (char*)d_ws;
    int*   cnt     = (int*)(ws + 0);                 // 160000 B
    int*   cursor  = (int*)(ws + 160000);            // 160000 B (zero region ends 320000)
    int*   row_ptr = (int*)(ws + 353024);            // 160016 B
    float* dinv    = (float*)(ws + 513088);          // 160000 B
    int*   csr_src = (int*)(ws + 673088);            // 2560000 B
    float* csr_w   = (float*)(ws + 3233088);         // 2560000 B
    float* bufA    = (float*)(ws + 5793088);         // 20480000 B
    float* bufB    = (float*)(ws + 26273088);        // 20480000 B (total ~46.8 MB)

    const int* src = eidx;             // edge_index[0]
    const int* dst = eidx + N_EDGES;   // edge_index[1]

    hipMemsetAsync(d_ws, 0, 320000, stream);
    k_degree<<<2500, 256, 0, stream>>>(dst, cnt);
    k_dinv<<<157, 256, 0, stream>>>(cnt, dinv);
    k_scan<<<1, 1024, 0, stream>>>(cnt, row_ptr);
    k_fill<<<2500, 256, 0, stream>>>(src, dst, row_ptr, cursor, dinv, csr_src, csr_w);

    k_gemm<<<512, 256, 0, stream>>>(x, W1, bufA);                       // xw1
    k_agg<<<10000, 256, 0, stream>>>(bufA, dinv, row_ptr, csr_src, csr_w, b1, bufB);
    k_gemm<<<512, 256, 0, stream>>>(bufB, W2, bufA);                    // h1@W2
    k_agg<<<10000, 256, 0, stream>>>(bufA, dinv, row_ptr, csr_src, csr_w, b2, bufB);
    k_pool<<<64, 128, 0, stream>>>(bufB, batch, lw, lb, out);
}

// Round 4
// 334.935 us; speedup vs baseline: 2.1894x; 1.4957x over previous
//
#include <hip/hip_runtime.h>
#include <stdint.h>

#define N_NODES 40000
#define N_EDGES 640000
#define HID 128
#define NGRAPH 64
#define NCLASS 10

typedef unsigned short u16;
typedef __attribute__((ext_vector_type(8))) short bf16x8;
typedef __attribute__((ext_vector_type(4))) float f32x4;

static __device__ __forceinline__ float bf2f(u16 u) {
    union { uint32_t i; float f; } v; v.i = ((uint32_t)u) << 16; return v.f;
}
static __device__ __forceinline__ u16 f2bf(float f) {
    union { float f; uint32_t i; } v; v.f = f;
    uint32_t u = v.i;
    u = (u + 0x7fff + ((u >> 16) & 1)) >> 16;   // RNE
    return (u16)u;
}

// ---------------- degree histogram over dst ----------------
__global__ void k_degree(const int* __restrict__ dst, int* __restrict__ cnt) {
    int e = blockIdx.x * blockDim.x + threadIdx.x;
    if (e < N_EDGES) atomicAdd(&cnt[dst[e]], 1);
}

// ---------------- dinv ----------------
__global__ void k_dinv(const int* __restrict__ cnt, float* __restrict__ dinv) {
    int i = blockIdx.x * blockDim.x + threadIdx.x;
    if (i < N_NODES) dinv[i] = rsqrtf((float)(cnt[i] + 1));  // +1 self-loop
}

// ---------------- exclusive scan of cnt -> row_ptr (single block, 1024 thr) ----------------
__global__ void k_scan(const int* __restrict__ cnt, int* __restrict__ row_ptr) {
    __shared__ int wsum[16];
    int t = threadIdx.x;
    int lane = t & 63, wv = t >> 6;
    int carry = 0;
    for (int base = 0; base < N_NODES; base += 1024) {
        int idx = base + t;
        int v = (idx < N_NODES) ? cnt[idx] : 0;
        int x = v;
        #pragma unroll
        for (int d = 1; d < 64; d <<= 1) {
            int y = __shfl_up(x, d, 64);
            if (lane >= d) x += y;
        }
        if (lane == 63) wsum[wv] = x;
        __syncthreads();
        int off = 0, tot = 0;
        #pragma unroll
        for (int w = 0; w < 16; ++w) {
            int s = wsum[w];
            if (w < wv) off += s;
            tot += s;
        }
        if (idx < N_NODES) row_ptr[idx] = carry + off + (x - v);
        carry += tot;
        __syncthreads();
    }
    if (t == 0) row_ptr[N_NODES] = carry;
}

// ---------------- CSR fill (grouped by dst) + per-edge weight ----------------
__global__ void k_fill(const int* __restrict__ srcs, const int* __restrict__ dsts,
                       const int* __restrict__ row_ptr, int* __restrict__ cursor,
                       const float* __restrict__ dinv,
                       int* __restrict__ csr_src, float* __restrict__ csr_w) {
    int e = blockIdx.x * blockDim.x + threadIdx.x;
    if (e < N_EDGES) {
        int s = srcs[e], d = dsts[e];
        int p = row_ptr[d] + atomicAdd(&cursor[d], 1);
        csr_src[p] = s;
        csr_w[p] = dinv[s] * dinv[d];
    }
}

// ---------------- bf16 MFMA GEMM: Out[40000,128] = A @ W[128,128] ----------------
// W (fp32 in HBM) staged bf16 in LDS pre-swizzled to B-fragment order.
// A_IS_F32: layer-1 reads fp32 x and converts; else reads bf16 rows.
template<bool A_IS_F32>
__launch_bounds__(256)
__global__ void k_gemm(const void* __restrict__ Ap, const float* __restrict__ W,
                       u16* __restrict__ Out) {
    __shared__ u16 wlds[32 * 64 * 8];   // 8 ntiles x 4 ksteps x 64 lanes x 8 bf16 = 32 KB
    int t = threadIdx.x;
    for (int idx = t; idx < 16384; idx += 256) {
        int j = idx & 7;
        int frag = idx >> 3;
        int l = frag & 63;
        int ks = (frag >> 6) & 3;
        int nt = frag >> 8;
        int k = ks * 32 + (l >> 4) * 8 + j;
        int n = nt * 16 + (l & 15);
        wlds[idx] = f2bf(W[k * HID + n]);
    }
    __syncthreads();

    int lane = t & 63, wv = t >> 6;
    int quad = lane >> 4, m15 = lane & 15;
    int strip = blockIdx.x * 4 + wv;        // 625 blocks x 4 waves = 2500 strips
    int m0 = strip * 16;

    bf16x8 af[4];
    if (A_IS_F32) {
        const float* arow = (const float*)Ap + (size_t)(m0 + m15) * HID;
        #pragma unroll
        for (int ks = 0; ks < 4; ++ks) {
            float4 u = *(const float4*)(arow + ks * 32 + quad * 8);
            float4 v = *(const float4*)(arow + ks * 32 + quad * 8 + 4);
            bf16x8 f;
            f[0] = (short)f2bf(u.x); f[1] = (short)f2bf(u.y);
            f[2] = (short)f2bf(u.z); f[3] = (short)f2bf(u.w);
            f[4] = (short)f2bf(v.x); f[5] = (short)f2bf(v.y);
            f[6] = (short)f2bf(v.z); f[7] = (short)f2bf(v.w);
            af[ks] = f;
        }
    } else {
        const u16* arow = (const u16*)Ap + (size_t)(m0 + m15) * HID;
        #pragma unroll
        for (int ks = 0; ks < 4; ++ks)
            af[ks] = *(const bf16x8*)(arow + ks * 32 + quad * 8);
    }

    #pragma unroll
    for (int nt = 0; nt < 8; ++nt) {
        f32x4 acc = {0.f, 0.f, 0.f, 0.f};
        #pragma unroll
        for (int ks = 0; ks < 4; ++ks) {
            bf16x8 bfr = *(const bf16x8*)(&wlds[((nt * 4 + ks) * 64 + lane) * 8]);
            acc = __builtin_amdgcn_mfma_f32_16x16x32_bf16(af[ks], bfr, acc, 0, 0, 0);
        }
        #pragma unroll
        for (int r = 0; r < 4; ++r)
            Out[(size_t)(m0 + quad * 4 + r) * HID + nt * 16 + m15] = f2bf(acc[r]);
    }
}

// ---------------- aggregation: out[i] = relu(dinv_i^2*y[i] + sum_e w_e*y[src_e] + b)
// bf16 rows: one wave per node, lane handles feats (2*lane, 2*lane+1) packed in u32.
__launch_bounds__(256, 8)
__global__ void k_agg(const u16* __restrict__ in, const float* __restrict__ dinv,
                      const int* __restrict__ row_ptr, const int* __restrict__ csr_src,
                      const float* __restrict__ csr_w, const float* __restrict__ bias,
                      u16* __restrict__ out) {
    int wid = (blockIdx.x * blockDim.x + threadIdx.x) >> 6;   // one wave per node
    int lane = threadIdx.x & 63;
    if (wid >= N_NODES) return;
    int i = wid;
    float di = dinv[i];
    uint32_t ps = *(const uint32_t*)(in + (size_t)i * HID + lane * 2);
    float a0 = bf2f((u16)(ps & 0xffff)) * di * di;
    float a1 = bf2f((u16)(ps >> 16)) * di * di;

    int e = row_ptr[i], e1 = row_ptr[i + 1];
    for (; e + 4 <= e1; e += 4) {
        int s0 = csr_src[e], s1 = csr_src[e + 1], s2 = csr_src[e + 2], s3 = csr_src[e + 3];
        float w0 = csr_w[e], w1 = csr_w[e + 1], w2 = csr_w[e + 2], w3 = csr_w[e + 3];
        uint32_t p0 = *(const uint32_t*)(in + (size_t)s0 * HID + lane * 2);
        uint32_t p1 = *(const uint32_t*)(in + (size_t)s1 * HID + lane * 2);
        uint32_t p2 = *(const uint32_t*)(in + (size_t)s2 * HID + lane * 2);
        uint32_t p3 = *(const uint32_t*)(in + (size_t)s3 * HID + lane * 2);
        a0 += w0 * bf2f((u16)(p0 & 0xffff));  a1 += w0 * bf2f((u16)(p0 >> 16));
        a0 += w1 * bf2f((u16)(p1 & 0xffff));  a1 += w1 * bf2f((u16)(p1 >> 16));
        a0 += w2 * bf2f((u16)(p2 & 0xffff));  a1 += w2 * bf2f((u16)(p2 >> 16));
        a0 += w3 * bf2f((u16)(p3 & 0xffff));  a1 += w3 * bf2f((u16)(p3 >> 16));
    }
    for (; e < e1; ++e) {
        int s = csr_src[e];
        float w = csr_w[e];
        uint32_t p = *(const uint32_t*)(in + (size_t)s * HID + lane * 2);
        a0 += w * bf2f((u16)(p & 0xffff));
        a1 += w * bf2f((u16)(p >> 16));
    }
    a0 = fmaxf(a0 + bias[lane * 2], 0.f);
    a1 = fmaxf(a1 + bias[lane * 2 + 1], 0.f);
    uint32_t o = (uint32_t)f2bf(a0) | ((uint32_t)f2bf(a1) << 16);
    *(uint32_t*)(out + (size_t)i * HID + lane * 2) = o;
}

// ---------------- pool + linear: one block per graph (batch sorted -> contiguous) ----
__launch_bounds__(128)
__global__ void k_pool(const u16* __restrict__ h, const int* __restrict__ batch,
                       const float* __restrict__ lin_w, const float* __restrict__ lin_b,
                       float* __restrict__ outp) {
    __shared__ float sh[HID];
    int g = blockIdx.x;
    int t = threadIdx.x;   // 128 threads, thread = feature
    int lo = 0, n = N_NODES;
    while (n > 0) { int half = n >> 1; int mid = lo + half;
        if (batch[mid] < g) { lo = mid + 1; n -= half + 1; } else n = half; }
    int hi = lo, n2 = N_NODES - lo;
    while (n2 > 0) { int half = n2 >> 1; int mid = hi + half;
        if (batch[mid] < g + 1) { hi = mid + 1; n2 -= half + 1; } else n2 = half; }
    float acc0 = 0.f, acc1 = 0.f, acc2 = 0.f, acc3 = 0.f;
    int r = lo;
    for (; r + 4 <= hi; r += 4) {
        acc0 += bf2f(h[(size_t)r * HID + t]);
        acc1 += bf2f(h[(size_t)(r + 1) * HID + t]);
        acc2 += bf2f(h[(size_t)(r + 2) * HID + t]);
        acc3 += bf2f(h[(size_t)(r + 3) * HID + t]);
    }
    for (; r < hi; ++r) acc0 += bf2f(h[(size_t)r * HID + t]);
    float c = fmaxf((float)(hi - lo), 1.f);
    sh[t] = (acc0 + acc1 + acc2 + acc3) / c;
    __syncthreads();
    if (t < NCLASS) {
        float acc = lin_b[t];
        #pragma unroll 8
        for (int f = 0; f < HID; ++f)
            acc += sh[f] * lin_w[f * NCLASS + t];
        outp[g * NCLASS + t] = acc;
    }
}

extern "C" void kernel_launch(void* const* d_in, const int* in_sizes, int n_in,
                              void* d_out, int out_size, void* d_ws, size_t ws_size,
                              hipStream_t stream) {
    const float* x    = (const float*)d_in[0];
    const int* eidx   = (const int*)d_in[1];
    const int* batch  = (const int*)d_in[2];
    const float* W1   = (const float*)d_in[3];
    const float* b1   = (const float*)d_in[4];
    const float* W2   = (const float*)d_in[5];
    const float* b2   = (const float*)d_in[6];
    const float* lw   = (const float*)d_in[7];
    const float* lb   = (const float*)d_in[8];
    float* out = (float*)d_out;

    char* ws = (char*)d_ws;
    int*   cnt     = (int*)(ws + 0);                 // 160000 B
    int*   cursor  = (int*)(ws + 160000);            // 160000 B (zero region ends 320000)
    int*   row_ptr = (int*)(ws + 353024);            // 160016 B
    float* dinv    = (float*)(ws + 513088);          // 160000 B
    int*   csr_src = (int*)(ws + 673088);            // 2560000 B
    float* csr_w   = (float*)(ws + 3233088);         // 2560000 B
    u16*   bufA    = (u16*)(ws + 5793088);           // 10240000 B (bf16 rows)
    u16*   bufB    = (u16*)(ws + 16033088);          // 10240000 B (total ~26.3 MB)

    const int* src = eidx;             // edge_index[0]
    const int* dst = eidx + N_EDGES;   // edge_index[1]

    hipMemsetAsync(d_ws, 0, 320000, stream);
    k_degree<<<2500, 256, 0, stream>>>(dst, cnt);
    k_dinv<<<157, 256, 0, stream>>>(cnt, dinv);
    k_scan<<<1, 1024, 0, stream>>>(cnt, row_ptr);
    k_fill<<<2500, 256, 0, stream>>>(src, dst, row_ptr, cursor, dinv, csr_src, csr_w);

    k_gemm<true><<<625, 256, 0, stream>>>(x, W1, bufA);                 // xw1 (bf16)
    k_agg<<<10000, 256, 0, stream>>>(bufA, dinv, row_ptr, csr_src, csr_w, b1, bufB);
    k_gemm<false><<<625, 256, 0, stream>>>(bufB, W2, bufA);             // h1@W2 (bf16)
    k_agg<<<10000, 256, 0, stream>>>(bufA, dinv, row_ptr, csr_src, csr_w, b2, bufB);
    k_pool<<<64, 128, 0, stream>>>(bufB, batch, lw, lb, out);
}

// Round 5
// 303.081 us; speedup vs baseline: 2.4195x; 1.1051x over previous
//
#include <hip/hip_runtime.h>
#include <stdint.h>

#define N_NODES 40000
#define N_EDGES 640000
#define HID 128
#define NGRAPH 64
#define NCLASS 10
#define NSPLIT 16

typedef unsigned short u16;
typedef __attribute__((ext_vector_type(8))) short bf16x8;
typedef __attribute__((ext_vector_type(4))) float f32x4;

static __device__ __forceinline__ float bf2f(u16 u) {
    union { uint32_t i; float f; } v; v.i = ((uint32_t)u) << 16; return v.f;
}
static __device__ __forceinline__ u16 f2bf(float f) {
    union { float f; uint32_t i; } v; v.f = f;
    uint32_t u = v.i;
    u = (u + 0x7fff + ((u >> 16) & 1)) >> 16;   // RNE
    return (u16)u;
}

// ---------------- degree histogram over dst ----------------
__global__ void k_degree(const int* __restrict__ dst, int* __restrict__ cnt) {
    int e = blockIdx.x * blockDim.x + threadIdx.x;
    if (e < N_EDGES) atomicAdd(&cnt[dst[e]], 1);
}

// ---------------- dinv ----------------
__global__ void k_dinv(const int* __restrict__ cnt, float* __restrict__ dinv) {
    int i = blockIdx.x * blockDim.x + threadIdx.x;
    if (i < N_NODES) dinv[i] = rsqrtf((float)(cnt[i] + 1));  // +1 self-loop
}

// ---------------- exclusive scan of cnt -> row_ptr (single block, 1024 thr) ----------------
__global__ void k_scan(const int* __restrict__ cnt, int* __restrict__ row_ptr) {
    __shared__ int wsum[16];
    int t = threadIdx.x;
    int lane = t & 63, wv = t >> 6;
    int carry = 0;
    for (int base = 0; base < N_NODES; base += 1024) {
        int idx = base + t;
        int v = (idx < N_NODES) ? cnt[idx] : 0;
        int x = v;
        #pragma unroll
        for (int d = 1; d < 64; d <<= 1) {
            int y = __shfl_up(x, d, 64);
            if (lane >= d) x += y;
        }
        if (lane == 63) wsum[wv] = x;
        __syncthreads();
        int off = 0, tot = 0;
        #pragma unroll
        for (int w = 0; w < 16; ++w) {
            int s = wsum[w];
            if (w < wv) off += s;
            tot += s;
        }
        if (idx < N_NODES) row_ptr[idx] = carry + off + (x - v);
        carry += tot;
        __syncthreads();
    }
    if (t == 0) row_ptr[N_NODES] = carry;
}

// ---------------- CSR fill (grouped by dst) + per-edge weight ----------------
__global__ void k_fill(const int* __restrict__ srcs, const int* __restrict__ dsts,
                       const int* __restrict__ row_ptr, int* __restrict__ cursor,
                       const float* __restrict__ dinv,
                       int* __restrict__ csr_src, float* __restrict__ csr_w) {
    int e = blockIdx.x * blockDim.x + threadIdx.x;
    if (e < N_EDGES) {
        int s = srcs[e], d = dsts[e];
        int p = row_ptr[d] + atomicAdd(&cursor[d], 1);
        csr_src[p] = s;
        csr_w[p] = dinv[s] * dinv[d];
    }
}

// ---------------- bf16 MFMA GEMM: Out[40000,128] = A @ W[128,128] ----------------
template<bool A_IS_F32>
__launch_bounds__(256)
__global__ void k_gemm(const void* __restrict__ Ap, const float* __restrict__ W,
                       u16* __restrict__ Out) {
    __shared__ u16 wlds[32 * 64 * 8];   // 8 ntiles x 4 ksteps x 64 lanes x 8 bf16 = 32 KB
    int t = threadIdx.x;
    for (int idx = t; idx < 16384; idx += 256) {
        int j = idx & 7;
        int frag = idx >> 3;
        int l = frag & 63;
        int ks = (frag >> 6) & 3;
        int nt = frag >> 8;
        int k = ks * 32 + (l >> 4) * 8 + j;
        int n = nt * 16 + (l & 15);
        wlds[idx] = f2bf(W[k * HID + n]);
    }
    __syncthreads();

    int lane = t & 63, wv = t >> 6;
    int quad = lane >> 4, m15 = lane & 15;
    int strip = blockIdx.x * 4 + wv;        // 625 blocks x 4 waves = 2500 strips
    int m0 = strip * 16;

    bf16x8 af[4];
    if (A_IS_F32) {
        const float* arow = (const float*)Ap + (size_t)(m0 + m15) * HID;
        #pragma unroll
        for (int ks = 0; ks < 4; ++ks) {
            float4 u = *(const float4*)(arow + ks * 32 + quad * 8);
            float4 v = *(const float4*)(arow + ks * 32 + quad * 8 + 4);
            bf16x8 f;
            f[0] = (short)f2bf(u.x); f[1] = (short)f2bf(u.y);
            f[2] = (short)f2bf(u.z); f[3] = (short)f2bf(u.w);
            f[4] = (short)f2bf(v.x); f[5] = (short)f2bf(v.y);
            f[6] = (short)f2bf(v.z); f[7] = (short)f2bf(v.w);
            af[ks] = f;
        }
    } else {
        const u16* arow = (const u16*)Ap + (size_t)(m0 + m15) * HID;
        #pragma unroll
        for (int ks = 0; ks < 4; ++ks)
            af[ks] = *(const bf16x8*)(arow + ks * 32 + quad * 8);
    }

    #pragma unroll
    for (int nt = 0; nt < 8; ++nt) {
        f32x4 acc = {0.f, 0.f, 0.f, 0.f};
        #pragma unroll
        for (int ks = 0; ks < 4; ++ks) {
            bf16x8 bfr = *(const bf16x8*)(&wlds[((nt * 4 + ks) * 64 + lane) * 8]);
            acc = __builtin_amdgcn_mfma_f32_16x16x32_bf16(af[ks], bfr, acc, 0, 0, 0);
        }
        #pragma unroll
        for (int r = 0; r < 4; ++r)
            Out[(size_t)(m0 + quad * 4 + r) * HID + nt * 16 + m15] = f2bf(acc[r]);
    }
}

// ---------------- aggregation: out[i] = relu(dinv_i^2*y[i] + sum_e w_e*y[src_e] + b)
__launch_bounds__(256, 8)
__global__ void k_agg(const u16* __restrict__ in, const float* __restrict__ dinv,
                      const int* __restrict__ row_ptr, const int* __restrict__ csr_src,
                      const float* __restrict__ csr_w, const float* __restrict__ bias,
                      u16* __restrict__ out) {
    int wid = (blockIdx.x * blockDim.x + threadIdx.x) >> 6;   // one wave per node
    int lane = threadIdx.x & 63;
    if (wid >= N_NODES) return;
    int i = wid;
    float di = dinv[i];
    uint32_t ps = *(const uint32_t*)(in + (size_t)i * HID + lane * 2);
    float a0 = bf2f((u16)(ps & 0xffff)) * di * di;
    float a1 = bf2f((u16)(ps >> 16)) * di * di;

    int e = row_ptr[i], e1 = row_ptr[i + 1];
    for (; e + 4 <= e1; e += 4) {
        int s0 = csr_src[e], s1 = csr_src[e + 1], s2 = csr_src[e + 2], s3 = csr_src[e + 3];
        float w0 = csr_w[e], w1 = csr_w[e + 1], w2 = csr_w[e + 2], w3 = csr_w[e + 3];
        uint32_t p0 = *(const uint32_t*)(in + (size_t)s0 * HID + lane * 2);
        uint32_t p1 = *(const uint32_t*)(in + (size_t)s1 * HID + lane * 2);
        uint32_t p2 = *(const uint32_t*)(in + (size_t)s2 * HID + lane * 2);
        uint32_t p3 = *(const uint32_t*)(in + (size_t)s3 * HID + lane * 2);
        a0 += w0 * bf2f((u16)(p0 & 0xffff));  a1 += w0 * bf2f((u16)(p0 >> 16));
        a0 += w1 * bf2f((u16)(p1 & 0xffff));  a1 += w1 * bf2f((u16)(p1 >> 16));
        a0 += w2 * bf2f((u16)(p2 & 0xffff));  a1 += w2 * bf2f((u16)(p2 >> 16));
        a0 += w3 * bf2f((u16)(p3 & 0xffff));  a1 += w3 * bf2f((u16)(p3 >> 16));
    }
    for (; e < e1; ++e) {
        int s = csr_src[e];
        float w = csr_w[e];
        uint32_t p = *(const uint32_t*)(in + (size_t)s * HID + lane * 2);
        a0 += w * bf2f((u16)(p & 0xffff));
        a1 += w * bf2f((u16)(p >> 16));
    }
    a0 = fmaxf(a0 + bias[lane * 2], 0.f);
    a1 = fmaxf(a1 + bias[lane * 2 + 1], 0.f);
    uint32_t o = (uint32_t)f2bf(a0) | ((uint32_t)f2bf(a1) << 16);
    *(uint32_t*)(out + (size_t)i * HID + lane * 2) = o;
}

// ---------------- pool stage 1: 64 graphs x 16 splits, partial sums (no atomics) ----
__launch_bounds__(256)
__global__ void k_pool1(const u16* __restrict__ h, const int* __restrict__ batch,
                        float* __restrict__ partial) {
    __shared__ float red[HID];
    int g = blockIdx.x >> 4;           // / NSPLIT
    int s = blockIdx.x & (NSPLIT - 1);
    int t = threadIdx.x;               // 256 thr: ty = row parity, tf = feature
    int ty = t >> 7, tf = t & 127;
    // graph g's contiguous node range [lo, hi) in sorted batch
    int lo = 0, n = N_NODES;
    while (n > 0) { int half = n >> 1; int mid = lo + half;
        if (batch[mid] < g) { lo = mid + 1; n -= half + 1; } else n = half; }
    int hi = lo, n2 = N_NODES - lo;
    while (n2 > 0) { int half = n2 >> 1; int mid = hi + half;
        if (batch[mid] < g + 1) { hi = mid + 1; n2 -= half + 1; } else n2 = half; }
    int len = (hi - lo + NSPLIT - 1) / NSPLIT;
    int r0 = lo + s * len;
    int r1 = min(r0 + len, hi);
    float acc = 0.f;
    for (int r = r0 + ty; r < r1; r += 2)
        acc += bf2f(h[(size_t)r * HID + tf]);
    if (ty == 1) red[tf] = acc;
    __syncthreads();
    if (ty == 0) partial[(size_t)blockIdx.x * HID + tf] = acc + red[tf];
}

// ---------------- pool stage 2: reduce 16 partials, mean, fused linear ----
__launch_bounds__(128)
__global__ void k_pool2(const float* __restrict__ partial, const int* __restrict__ batch,
                        const float* __restrict__ lin_w, const float* __restrict__ lin_b,
                        float* __restrict__ outp) {
    __shared__ float sh[HID];
    int g = blockIdx.x;
    int t = threadIdx.x;   // 128 threads, thread = feature
    int lo = 0, n = N_NODES;
    while (n > 0) { int half = n >> 1; int mid = lo + half;
        if (batch[mid] < g) { lo = mid + 1; n -= half + 1; } else n = half; }
    int hi = lo, n2 = N_NODES - lo;
    while (n2 > 0) { int half = n2 >> 1; int mid = hi + half;
        if (batch[mid] < g + 1) { hi = mid + 1; n2 -= half + 1; } else n2 = half; }
    float acc = 0.f;
    #pragma unroll
    for (int s = 0; s < NSPLIT; ++s)
        acc += partial[(size_t)(g * NSPLIT + s) * HID + t];
    float c = fmaxf((float)(hi - lo), 1.f);
    sh[t] = acc / c;
    __syncthreads();
    if (t < NCLASS) {
        float a = lin_b[t];
        #pragma unroll 8
        for (int f = 0; f < HID; ++f)
            a += sh[f] * lin_w[f * NCLASS + t];
        outp[g * NCLASS + t] = a;
    }
}

extern "C" void kernel_launch(void* const* d_in, const int* in_sizes, int n_in,
                              void* d_out, int out_size, void* d_ws, size_t ws_size,
                              hipStream_t stream) {
    const float* x    = (const float*)d_in[0];
    const int* eidx   = (const int*)d_in[1];
    const int* batch  = (const int*)d_in[2];
    const float* W1   = (const float*)d_in[3];
    const float* b1   = (const float*)d_in[4];
    const float* W2   = (const float*)d_in[5];
    const float* b2   = (const float*)d_in[6];
    const float* lw   = (const float*)d_in[7];
    const float* lb   = (const float*)d_in[8];
    float* out = (float*)d_out;

    char* ws = (char*)d_ws;
    int*   cnt     = (int*)(ws + 0);                 // 160000 B
    int*   cursor  = (int*)(ws + 160000);            // 160000 B (zero region ends 320000)
    float* partial = (float*)(ws + 320000);          // 1024*128*4 = 524288 B
    int*   row_ptr = (int*)(ws + 844288);            // 160016 B
    float* dinv    = (float*)(ws + 1004304);         // 160000 B
    int*   csr_src = (int*)(ws + 1164304);           // 2560000 B
    float* csr_w   = (float*)(ws + 3724304);         // 2560000 B
    u16*   bufA    = (u16*)(ws + 6284304);           // 10240000 B (bf16 rows)
    u16*   bufB    = (u16*)(ws + 16524304);          // 10240000 B (total ~26.8 MB)

    const int* src = eidx;             // edge_index[0]
    const int* dst = eidx + N_EDGES;   // edge_index[1]

    hipMemsetAsync(d_ws, 0, 320000, stream);
    k_degree<<<2500, 256, 0, stream>>>(dst, cnt);
    k_dinv<<<157, 256, 0, stream>>>(cnt, dinv);
    k_scan<<<1, 1024, 0, stream>>>(cnt, row_ptr);
    k_fill<<<2500, 256, 0, stream>>>(src, dst, row_ptr, cursor, dinv, csr_src, csr_w);

    k_gemm<true><<<625, 256, 0, stream>>>(x, W1, bufA);                 // xw1 (bf16)
    k_agg<<<10000, 256, 0, stream>>>(bufA, dinv, row_ptr, csr_src, csr_w, b1, bufB);
    k_gemm<false><<<625, 256, 0, stream>>>(bufB, W2, bufA);             // h1@W2 (bf16)
    k_agg<<<10000, 256, 0, stream>>>(bufA, dinv, row_ptr, csr_src, csr_w, b2, bufB);
    k_pool1<<<NGRAPH * NSPLIT, 256, 0, stream>>>(bufB, batch, partial);
    k_pool2<<<NGRAPH, 128, 0, stream>>>(partial, batch, lw, lb, out);
}

// Round 6
// 263.551 us; speedup vs baseline: 2.7824x; 1.1500x over previous
//
#include <hip/hip_runtime.h>
#include <stdint.h>

#define N_NODES 40000
#define N_EDGES 640000
#define HID 128
#define NGRAPH 64
#define NCLASS 10
#define NSPLIT 16

typedef unsigned short u16;
typedef __attribute__((ext_vector_type(8))) short bf16x8;
typedef __attribute__((ext_vector_type(4))) float f32x4;

static __device__ __forceinline__ float bf2f(u16 u) {
    union { uint32_t i; float f; } v; v.i = ((uint32_t)u) << 16; return v.f;
}
static __device__ __forceinline__ u16 f2bf(float f) {
    union { float f; uint32_t i; } v; v.f = f;
    uint32_t u = v.i;
    u = (u + 0x7fff + ((u >> 16) & 1)) >> 16;   // RNE
    return (u16)u;
}

// ---------------- degree histogram over dst ----------------
__global__ void k_degree(const int* __restrict__ dst, int* __restrict__ cnt) {
    int e = blockIdx.x * blockDim.x + threadIdx.x;
    if (e < N_EDGES) atomicAdd(&cnt[dst[e]], 1);
}

// ---------------- scan stage 1: fused dinv + per-block (256-wide) local exclusive scan ----
// rploc[idx] = exclusive scan within block; bsum[b] = block total.
// global row_ptr[j] = rploc[j] + boff[j>>8], reconstructed on the fly by consumers.
__launch_bounds__(256)
__global__ void k_scan1(const int* __restrict__ cnt, float* __restrict__ dinv,
                        int* __restrict__ rploc, int* __restrict__ bsum) {
    __shared__ int wsum[4];
    int t = threadIdx.x;
    int idx = blockIdx.x * 256 + t;           // grid 157 -> idx < 40192
    int v = (idx < N_NODES) ? cnt[idx] : 0;
    if (idx < N_NODES) dinv[idx] = rsqrtf((float)(v + 1));   // +1 self-loop
    int lane = t & 63, wv = t >> 6;
    int x = v;
    #pragma unroll
    for (int d = 1; d < 64; d <<= 1) {
        int y = __shfl_up(x, d, 64);
        if (lane >= d) x += y;
    }
    if (lane == 63) wsum[wv] = x;
    __syncthreads();
    int off = 0;
    #pragma unroll
    for (int w = 0; w < 4; ++w) { int s = wsum[w]; if (w < wv) off += s; }
    rploc[idx] = off + x - v;                 // local exclusive
    if (t == 255) bsum[blockIdx.x] = off + x; // block total
}

// ---------------- scan stage 2: exclusive scan of 157 block sums -> boff ----------------
__launch_bounds__(256)
__global__ void k_scan2(const int* __restrict__ bsum, int* __restrict__ boff) {
    __shared__ int wsum[4];
    int t = threadIdx.x;
    int v = (t < 157) ? bsum[t] : 0;
    int lane = t & 63, wv = t >> 6;
    int x = v;
    #pragma unroll
    for (int d = 1; d < 64; d <<= 1) {
        int y = __shfl_up(x, d, 64);
        if (lane >= d) x += y;
    }
    if (lane == 63) wsum[wv] = x;
    __syncthreads();
    int off = 0;
    #pragma unroll
    for (int w = 0; w < 4; ++w) { int s = wsum[w]; if (w < wv) off += s; }
    if (t < 157) boff[t] = off + x - v;
}

// ---------------- CSR fill (grouped by dst) + per-edge weight ----------------
__global__ void k_fill(const int* __restrict__ srcs, const int* __restrict__ dsts,
                       const int* __restrict__ rploc, const int* __restrict__ boff,
                       int* __restrict__ cursor, const float* __restrict__ dinv,
                       int* __restrict__ csr_src, float* __restrict__ csr_w) {
    int e = blockIdx.x * blockDim.x + threadIdx.x;
    if (e < N_EDGES) {
        int s = srcs[e], d = dsts[e];
        int p = rploc[d] + boff[d >> 8] + atomicAdd(&cursor[d], 1);
        csr_src[p] = s;
        csr_w[p] = dinv[s] * dinv[d];
    }
}

// ---------------- bf16 MFMA GEMM: Out[40000,128] = A @ W[128,128] ----------------
template<bool A_IS_F32>
__launch_bounds__(256)
__global__ void k_gemm(const void* __restrict__ Ap, const float* __restrict__ W,
                       u16* __restrict__ Out) {
    __shared__ u16 wlds[32 * 64 * 8];   // 8 ntiles x 4 ksteps x 64 lanes x 8 bf16 = 32 KB
    int t = threadIdx.x;
    for (int idx = t; idx < 16384; idx += 256) {
        int j = idx & 7;
        int frag = idx >> 3;
        int l = frag & 63;
        int ks = (frag >> 6) & 3;
        int nt = frag >> 8;
        int k = ks * 32 + (l >> 4) * 8 + j;
        int n = nt * 16 + (l & 15);
        wlds[idx] = f2bf(W[k * HID + n]);
    }
    __syncthreads();

    int lane = t & 63, wv = t >> 6;
    int quad = lane >> 4, m15 = lane & 15;
    int strip = blockIdx.x * 4 + wv;        // 625 blocks x 4 waves = 2500 strips
    int m0 = strip * 16;

    bf16x8 af[4];
    if (A_IS_F32) {
        const float* arow = (const float*)Ap + (size_t)(m0 + m15) * HID;
        #pragma unroll
        for (int ks = 0; ks < 4; ++ks) {
            float4 u = *(const float4*)(arow + ks * 32 + quad * 8);
            float4 v = *(const float4*)(arow + ks * 32 + quad * 8 + 4);
            bf16x8 f;
            f[0] = (short)f2bf(u.x); f[1] = (short)f2bf(u.y);
            f[2] = (short)f2bf(u.z); f[3] = (short)f2bf(u.w);
            f[4] = (short)f2bf(v.x); f[5] = (short)f2bf(v.y);
            f[6] = (short)f2bf(v.z); f[7] = (short)f2bf(v.w);
            af[ks] = f;
        }
    } else {
        const u16* arow = (const u16*)Ap + (size_t)(m0 + m15) * HID;
        #pragma unroll
        for (int ks = 0; ks < 4; ++ks)
            af[ks] = *(const bf16x8*)(arow + ks * 32 + quad * 8);
    }

    #pragma unroll
    for (int nt = 0; nt < 8; ++nt) {
        f32x4 acc = {0.f, 0.f, 0.f, 0.f};
        #pragma unroll
        for (int ks = 0; ks < 4; ++ks) {
            bf16x8 bfr = *(const bf16x8*)(&wlds[((nt * 4 + ks) * 64 + lane) * 8]);
            acc = __builtin_amdgcn_mfma_f32_16x16x32_bf16(af[ks], bfr, acc, 0, 0, 0);
        }
        #pragma unroll
        for (int r = 0; r < 4; ++r)
            Out[(size_t)(m0 + quad * 4 + r) * HID + nt * 16 + m15] = f2bf(acc[r]);
    }
}

// ---------------- aggregation: out[i] = relu(dinv_i^2*y[i] + sum_e w_e*y[src_e] + b)
__launch_bounds__(256, 8)
__global__ void k_agg(const u16* __restrict__ in, const float* __restrict__ dinv,
                      const int* __restrict__ rploc, const int* __restrict__ boff,
                      const int* __restrict__ csr_src, const float* __restrict__ csr_w,
                      const float* __restrict__ bias, u16* __restrict__ out) {
    int wid = (blockIdx.x * blockDim.x + threadIdx.x) >> 6;   // one wave per node
    int lane = threadIdx.x & 63;
    if (wid >= N_NODES) return;
    int i = wid;
    float di = dinv[i];
    uint32_t ps = *(const uint32_t*)(in + (size_t)i * HID + lane * 2);
    float a0 = bf2f((u16)(ps & 0xffff)) * di * di;
    float a1 = bf2f((u16)(ps >> 16)) * di * di;

    int e  = rploc[i] + boff[i >> 8];
    int e1 = rploc[i + 1] + boff[(i + 1) >> 8];
    for (; e + 4 <= e1; e += 4) {
        int s0 = csr_src[e], s1 = csr_src[e + 1], s2 = csr_src[e + 2], s3 = csr_src[e + 3];
        float w0 = csr_w[e], w1 = csr_w[e + 1], w2 = csr_w[e + 2], w3 = csr_w[e + 3];
        uint32_t p0 = *(const uint32_t*)(in + (size_t)s0 * HID + lane * 2);
        uint32_t p1 = *(const uint32_t*)(in + (size_t)s1 * HID + lane * 2);
        uint32_t p2 = *(const uint32_t*)(in + (size_t)s2 * HID + lane * 2);
        uint32_t p3 = *(const uint32_t*)(in + (size_t)s3 * HID + lane * 2);
        a0 += w0 * bf2f((u16)(p0 & 0xffff));  a1 += w0 * bf2f((u16)(p0 >> 16));
        a0 += w1 * bf2f((u16)(p1 & 0xffff));  a1 += w1 * bf2f((u16)(p1 >> 16));
        a0 += w2 * bf2f((u16)(p2 & 0xffff));  a1 += w2 * bf2f((u16)(p2 >> 16));
        a0 += w3 * bf2f((u16)(p3 & 0xffff));  a1 += w3 * bf2f((u16)(p3 >> 16));
    }
    for (; e < e1; ++e) {
        int s = csr_src[e];
        float w = csr_w[e];
        uint32_t p = *(const uint32_t*)(in + (size_t)s * HID + lane * 2);
        a0 += w * bf2f((u16)(p & 0xffff));
        a1 += w * bf2f((u16)(p >> 16));
    }
    a0 = fmaxf(a0 + bias[lane * 2], 0.f);
    a1 = fmaxf(a1 + bias[lane * 2 + 1], 0.f);
    uint32_t o = (uint32_t)f2bf(a0) | ((uint32_t)f2bf(a1) << 16);
    *(uint32_t*)(out + (size_t)i * HID + lane * 2) = o;
}

// ---------------- pool stage 1: 64 graphs x 16 splits, partial sums (no atomics) ----
__launch_bounds__(256)
__global__ void k_pool1(const u16* __restrict__ h, const int* __restrict__ batch,
                        float* __restrict__ partial) {
    __shared__ float red[HID];
    int g = blockIdx.x >> 4;           // / NSPLIT
    int s = blockIdx.x & (NSPLIT - 1);
    int t = threadIdx.x;               // 256 thr: ty = row parity, tf = feature
    int ty = t >> 7, tf = t & 127;
    int lo = 0, n = N_NODES;
    while (n > 0) { int half = n >> 1; int mid = lo + half;
        if (batch[mid] < g) { lo = mid + 1; n -= half + 1; } else n = half; }
    int hi = lo, n2 = N_NODES - lo;
    while (n2 > 0) { int half = n2 >> 1; int mid = hi + half;
        if (batch[mid] < g + 1) { hi = mid + 1; n2 -= half + 1; } else n2 = half; }
    int len = (hi - lo + NSPLIT - 1) / NSPLIT;
    int r0 = lo + s * len;
    int r1 = min(r0 + len, hi);
    float acc = 0.f;
    for (int r = r0 + ty; r < r1; r += 2)
        acc += bf2f(h[(size_t)r * HID + tf]);
    if (ty == 1) red[tf] = acc;
    __syncthreads();
    if (ty == 0) partial[(size_t)blockIdx.x * HID + tf] = acc + red[tf];
}

// ---------------- pool stage 2: reduce 16 partials, mean, fused linear ----------------
__launch_bounds__(128)
__global__ void k_pool2(const float* __restrict__ partial, const int* __restrict__ batch,
                        const float* __restrict__ lin_w, const float* __restrict__ lin_b,
                        float* __restrict__ outp) {
    __shared__ float sh[HID];
    int g = blockIdx.x;
    int t = threadIdx.x;   // 128 threads, thread = feature
    int lo = 0, n = N_NODES;
    while (n > 0) { int half = n >> 1; int mid = lo + half;
        if (batch[mid] < g) { lo = mid + 1; n -= half + 1; } else n = half; }
    int hi = lo, n2 = N_NODES - lo;
    while (n2 > 0) { int half = n2 >> 1; int mid = hi + half;
        if (batch[mid] < g + 1) { hi = mid + 1; n2 -= half + 1; } else n2 = half; }
    float acc = 0.f;
    #pragma unroll
    for (int s = 0; s < NSPLIT; ++s)
        acc += partial[(size_t)(g * NSPLIT + s) * HID + t];
    float c = fmaxf((float)(hi - lo), 1.f);
    sh[t] = acc / c;
    __syncthreads();
    if (t < NCLASS) {
        float a = lin_b[t];
        #pragma unroll 8
        for (int f = 0; f < HID; ++f)
            a += sh[f] * lin_w[f * NCLASS + t];
        outp[g * NCLASS + t] = a;
    }
}

extern "C" void kernel_launch(void* const* d_in, const int* in_sizes, int n_in,
                              void* d_out, int out_size, void* d_ws, size_t ws_size,
                              hipStream_t stream) {
    const float* x    = (const float*)d_in[0];
    const int* eidx   = (const int*)d_in[1];
    const int* batch  = (const int*)d_in[2];
    const float* W1   = (const float*)d_in[3];
    const float* b1   = (const float*)d_in[4];
    const float* W2   = (const float*)d_in[5];
    const float* b2   = (const float*)d_in[6];
    const float* lw   = (const float*)d_in[7];
    const float* lb   = (const float*)d_in[8];
    float* out = (float*)d_out;

    char* ws = (char*)d_ws;
    int*   cnt     = (int*)(ws + 0);                 // 160000 B
    int*   cursor  = (int*)(ws + 160000);            // 160000 B (zero region [0,320000))
    int*   bsum    = (int*)(ws + 320000);            // 1024 B
    int*   boff    = (int*)(ws + 321024);            // 1024 B
    int*   rploc   = (int*)(ws + 322048);            // 160768 B (40192 ints)
    float* dinv    = (float*)(ws + 482816);          // 160000 B
    int*   csr_src = (int*)(ws + 642816);            // 2560000 B
    float* csr_w   = (float*)(ws + 3202816);         // 2560000 B
    float* partial = (float*)(ws + 5762816);         // 524288 B
    u16*   bufA    = (u16*)(ws + 6287104);           // 10240000 B (bf16 rows)
    u16*   bufB    = (u16*)(ws + 16527104);          // 10240000 B (total ~26.8 MB)

    const int* src = eidx;             // edge_index[0]
    const int* dst = eidx + N_EDGES;   // edge_index[1]

    hipMemsetAsync(d_ws, 0, 320000, stream);
    k_degree<<<2500, 256, 0, stream>>>(dst, cnt);
    k_scan1<<<157, 256, 0, stream>>>(cnt, dinv, rploc, bsum);   // fused dinv + local scan
    k_scan2<<<1, 256, 0, stream>>>(bsum, boff);
    k_fill<<<2500, 256, 0, stream>>>(src, dst, rploc, boff, cursor, dinv, csr_src, csr_w);

    k_gemm<true><<<625, 256, 0, stream>>>(x, W1, bufA);                 // xw1 (bf16)
    k_agg<<<10000, 256, 0, stream>>>(bufA, dinv, rploc, boff, csr_src, csr_w, b1, bufB);
    k_gemm<false><<<625, 256, 0, stream>>>(bufB, W2, bufA);             // h1@W2 (bf16)
    k_agg<<<10000, 256, 0, stream>>>(bufA, dinv, rploc, boff, csr_src, csr_w, b2, bufB);
    k_pool1<<<NGRAPH * NSPLIT, 256, 0, stream>>>(bufB, batch, partial);
    k_pool2<<<NGRAPH, 128, 0, stream>>>(partial, batch, lw, lb, out);
}

// Round 7
// 250.619 us; speedup vs baseline: 2.9259x; 1.0516x over previous
//
#include <hip/hip_runtime.h>
#include <stdint.h>

#define N_NODES 40000
#define N_EDGES 640000
#define HID 128
#define NGRAPH 64
#define NCLASS 10
#define NSPLIT 16

typedef unsigned short u16;
typedef __attribute__((ext_vector_type(8))) short bf16x8;
typedef __attribute__((ext_vector_type(4))) float f32x4;

static __device__ __forceinline__ float bf2f(u16 u) {
    union { uint32_t i; float f; } v; v.i = ((uint32_t)u) << 16; return v.f;
}
static __device__ __forceinline__ u16 f2bf(float f) {
    union { float f; uint32_t i; } v; v.f = f;
    uint32_t u = v.i;
    u = (u + 0x7fff + ((u >> 16) & 1)) >> 16;   // RNE
    return (u16)u;
}

// ---------------- degree histogram over dst ----------------
__global__ void k_degree(const int* __restrict__ dst, int* __restrict__ cnt) {
    int e = blockIdx.x * blockDim.x + threadIdx.x;
    if (e < N_EDGES) atomicAdd(&cnt[dst[e]], 1);
}

// ---------------- scan stage 1: fused dinv + per-block (256) local exclusive scan ----
__launch_bounds__(256)
__global__ void k_scan1(const int* __restrict__ cnt, float* __restrict__ dinv,
                        int* __restrict__ rploc, int* __restrict__ bsum) {
    __shared__ int wsum[4];
    int t = threadIdx.x;
    int idx = blockIdx.x * 256 + t;           // grid 157 -> idx < 40192
    int v = (idx < N_NODES) ? cnt[idx] : 0;
    if (idx < N_NODES) dinv[idx] = rsqrtf((float)(v + 1));   // +1 self-loop
    int lane = t & 63, wv = t >> 6;
    int x = v;
    #pragma unroll
    for (int d = 1; d < 64; d <<= 1) {
        int y = __shfl_up(x, d, 64);
        if (lane >= d) x += y;
    }
    if (lane == 63) wsum[wv] = x;
    __syncthreads();
    int off = 0;
    #pragma unroll
    for (int w = 0; w < 4; ++w) { int s = wsum[w]; if (w < wv) off += s; }
    rploc[idx] = off + x - v;                 // local exclusive
    if (t == 255) bsum[blockIdx.x] = off + x; // block total
}

// ---------------- scan stage 2: exclusive scan of 157 block sums -> boff ----------------
__launch_bounds__(256)
__global__ void k_scan2(const int* __restrict__ bsum, int* __restrict__ boff) {
    __shared__ int wsum[4];
    int t = threadIdx.x;
    int v = (t < 157) ? bsum[t] : 0;
    int lane = t & 63, wv = t >> 6;
    int x = v;
    #pragma unroll
    for (int d = 1; d < 64; d <<= 1) {
        int y = __shfl_up(x, d, 64);
        if (lane >= d) x += y;
    }
    if (lane == 63) wsum[wv] = x;
    __syncthreads();
    int off = 0;
    #pragma unroll
    for (int w = 0; w < 4; ++w) { int s = wsum[w]; if (w < wv) off += s; }
    if (t < 157) boff[t] = off + x - v;
}

// ---------------- CSR fill: slot via count-down on cnt (cursor-free); (src,w) packed ----
__global__ void k_fill(const int* __restrict__ srcs, const int* __restrict__ dsts,
                       const int* __restrict__ rploc, const int* __restrict__ boff,
                       int* __restrict__ cnt, const float* __restrict__ dinv,
                       int2* __restrict__ csr) {
    int e = blockIdx.x * blockDim.x + threadIdx.x;
    if (e < N_EDGES) {
        int s = srcs[e], d = dsts[e];
        int old = atomicSub(&cnt[d], 1);                 // old in [1, deg]
        int p = rploc[d] + boff[d >> 8] + old - 1;
        float w = dinv[s] * dinv[d];
        csr[p] = make_int2(s, __float_as_int(w));
    }
}

// ---------------- W pre-swizzle: fp32 W1,W2 -> bf16 in B-fragment order ----------------
// idx<16384 per matrix: j=idx&7, frag=idx>>3, l=frag&63, ks=(frag>>6)&3, nt=frag>>8
// k = ks*32+(l>>4)*8+j ; n = nt*16+(l&15)
__launch_bounds__(256)
__global__ void k_wprep(const float* __restrict__ W1, const float* __restrict__ W2,
                        u16* __restrict__ wswz1, u16* __restrict__ wswz2) {
    int gid = blockIdx.x * 256 + threadIdx.x;     // grid 128 -> 32768 threads
    int idx = gid & 16383;
    const float* W = (gid < 16384) ? W1 : W2;
    u16* o = (gid < 16384) ? wswz1 : wswz2;
    int j = idx & 7;
    int frag = idx >> 3;
    int l = frag & 63;
    int ks = (frag >> 6) & 3;
    int nt = frag >> 8;
    int k = ks * 32 + (l >> 4) * 8 + j;
    int n = nt * 16 + (l & 15);
    o[idx] = f2bf(W[k * HID + n]);
}

// ---------------- bf16 MFMA GEMM: Out[40000,128] = A @ W, W pre-swizzled bf16 ----------
template<bool A_IS_F32>
__launch_bounds__(256)
__global__ void k_gemm(const void* __restrict__ Ap, const u16* __restrict__ wswz,
                       u16* __restrict__ Out) {
    __shared__ u16 wlds[32 * 64 * 8];   // 32 KB
    int t = threadIdx.x;
    {   // vectorized stage: 2048 uint4 / 256 thr = 8 iters
        const uint4* s4 = (const uint4*)wswz;
        uint4* d4 = (uint4*)wlds;
        #pragma unroll
        for (int i = 0; i < 8; ++i) d4[t + 256 * i] = s4[t + 256 * i];
    }
    __syncthreads();

    int lane = t & 63, wv = t >> 6;
    int quad = lane >> 4, m15 = lane & 15;
    int strip = blockIdx.x * 4 + wv;        // 625 blocks x 4 waves = 2500 strips
    int m0 = strip * 16;

    bf16x8 af[4];
    if (A_IS_F32) {
        const float* arow = (const float*)Ap + (size_t)(m0 + m15) * HID;
        #pragma unroll
        for (int ks = 0; ks < 4; ++ks) {
            float4 u = *(const float4*)(arow + ks * 32 + quad * 8);
            float4 v = *(const float4*)(arow + ks * 32 + quad * 8 + 4);
            bf16x8 f;
            f[0] = (short)f2bf(u.x); f[1] = (short)f2bf(u.y);
            f[2] = (short)f2bf(u.z); f[3] = (short)f2bf(u.w);
            f[4] = (short)f2bf(v.x); f[5] = (short)f2bf(v.y);
            f[6] = (short)f2bf(v.z); f[7] = (short)f2bf(v.w);
            af[ks] = f;
        }
    } else {
        const u16* arow = (const u16*)Ap + (size_t)(m0 + m15) * HID;
        #pragma unroll
        for (int ks = 0; ks < 4; ++ks)
            af[ks] = *(const bf16x8*)(arow + ks * 32 + quad * 8);
    }

    #pragma unroll
    for (int nt = 0; nt < 8; ++nt) {
        f32x4 acc = {0.f, 0.f, 0.f, 0.f};
        #pragma unroll
        for (int ks = 0; ks < 4; ++ks) {
            bf16x8 bfr = *(const bf16x8*)(&wlds[((nt * 4 + ks) * 64 + lane) * 8]);
            acc = __builtin_amdgcn_mfma_f32_16x16x32_bf16(af[ks], bfr, acc, 0, 0, 0);
        }
        #pragma unroll
        for (int r = 0; r < 4; ++r)
            Out[(size_t)(m0 + quad * 4 + r) * HID + nt * 16 + m15] = f2bf(acc[r]);
    }
}

// ---------------- aggregation: out[i] = relu(dinv_i^2*y[i] + sum_e w_e*y[src_e] + b)
// one wave per node; lane = feats (2*lane, 2*lane+1); (src,w) packed int2; unroll 8.
__launch_bounds__(256, 4)
__global__ void k_agg(const u16* __restrict__ in, const float* __restrict__ dinv,
                      const int* __restrict__ rploc, const int* __restrict__ boff,
                      const int2* __restrict__ csr, const float* __restrict__ bias,
                      u16* __restrict__ out) {
    int wid = (blockIdx.x * blockDim.x + threadIdx.x) >> 6;   // one wave per node
    int lane = threadIdx.x & 63;
    if (wid >= N_NODES) return;
    int i = wid;
    float di = dinv[i];
    uint32_t ps = *(const uint32_t*)(in + (size_t)i * HID + lane * 2);
    float a0 = bf2f((u16)(ps & 0xffff)) * di * di;
    float a1 = bf2f((u16)(ps >> 16)) * di * di;

    int e  = rploc[i] + boff[i >> 8];
    int e1 = rploc[i + 1] + boff[(i + 1) >> 8];
    for (; e + 8 <= e1; e += 8) {
        int2 c[8];
        uint32_t p[8];
        #pragma unroll
        for (int u = 0; u < 8; ++u) c[u] = csr[e + u];
        #pragma unroll
        for (int u = 0; u < 8; ++u)
            p[u] = *(const uint32_t*)(in + (size_t)c[u].x * HID + lane * 2);
        #pragma unroll
        for (int u = 0; u < 8; ++u) {
            float w = __int_as_float(c[u].y);
            a0 += w * bf2f((u16)(p[u] & 0xffff));
            a1 += w * bf2f((u16)(p[u] >> 16));
        }
    }
    for (; e < e1; ++e) {
        int2 c = csr[e];
        float w = __int_as_float(c.y);
        uint32_t p = *(const uint32_t*)(in + (size_t)c.x * HID + lane * 2);
        a0 += w * bf2f((u16)(p & 0xffff));
        a1 += w * bf2f((u16)(p >> 16));
    }
    a0 = fmaxf(a0 + bias[lane * 2], 0.f);
    a1 = fmaxf(a1 + bias[lane * 2 + 1], 0.f);
    uint32_t o = (uint32_t)f2bf(a0) | ((uint32_t)f2bf(a1) << 16);
    *(uint32_t*)(out + (size_t)i * HID + lane * 2) = o;
}

// ---------------- pool stage 1: 64 graphs x 16 splits, partial sums (no atomics) ----
__launch_bounds__(256)
__global__ void k_pool1(const u16* __restrict__ h, const int* __restrict__ batch,
                        float* __restrict__ partial) {
    __shared__ float red[HID];
    int g = blockIdx.x >> 4;           // / NSPLIT
    int s = blockIdx.x & (NSPLIT - 1);
    int t = threadIdx.x;               // 256 thr: ty = row parity, tf = feature
    int ty = t >> 7, tf = t & 127;
    int lo = 0, n = N_NODES;
    while (n > 0) { int half = n >> 1; int mid = lo + half;
        if (batch[mid] < g) { lo = mid + 1; n -= half + 1; } else n = half; }
    int hi = lo, n2 = N_NODES - lo;
    while (n2 > 0) { int half = n2 >> 1; int mid = hi + half;
        if (batch[mid] < g + 1) { hi = mid + 1; n2 -= half + 1; } else n2 = half; }
    int len = (hi - lo + NSPLIT - 1) / NSPLIT;
    int r0 = lo + s * len;
    int r1 = min(r0 + len, hi);
    float acc = 0.f;
    for (int r = r0 + ty; r < r1; r += 2)
        acc += bf2f(h[(size_t)r * HID + tf]);
    if (ty == 1) red[tf] = acc;
    __syncthreads();
    if (ty == 0) partial[(size_t)blockIdx.x * HID + tf] = acc + red[tf];
}

// ---------------- pool stage 2: reduce 16 partials, mean, fused linear ----------------
__launch_bounds__(128)
__global__ void k_pool2(const float* __restrict__ partial, const int* __restrict__ batch,
                        const float* __restrict__ lin_w, const float* __restrict__ lin_b,
                        float* __restrict__ outp) {
    __shared__ float sh[HID];
    int g = blockIdx.x;
    int t = threadIdx.x;   // 128 threads, thread = feature
    int lo = 0, n = N_NODES;
    while (n > 0) { int half = n >> 1; int mid = lo + half;
        if (batch[mid] < g) { lo = mid + 1; n -= half + 1; } else n = half; }
    int hi = lo, n2 = N_NODES - lo;
    while (n2 > 0) { int half = n2 >> 1; int mid = hi + half;
        if (batch[mid] < g + 1) { hi = mid + 1; n2 -= half + 1; } else n2 = half; }
    float acc = 0.f;
    #pragma unroll
    for (int s = 0; s < NSPLIT; ++s)
        acc += partial[(size_t)(g * NSPLIT + s) * HID + t];
    float c = fmaxf((float)(hi - lo), 1.f);
    sh[t] = acc / c;
    __syncthreads();
    if (t < NCLASS) {
        float a = lin_b[t];
        #pragma unroll 8
        for (int f = 0; f < HID; ++f)
            a += sh[f] * lin_w[f * NCLASS + t];
        outp[g * NCLASS + t] = a;
    }
}

extern "C" void kernel_launch(void* const* d_in, const int* in_sizes, int n_in,
                              void* d_out, int out_size, void* d_ws, size_t ws_size,
                              hipStream_t stream) {
    const float* x    = (const float*)d_in[0];
    const int* eidx   = (const int*)d_in[1];
    const int* batch  = (const int*)d_in[2];
    const float* W1   = (const float*)d_in[3];
    const float* b1   = (const float*)d_in[4];
    const float* W2   = (const float*)d_in[5];
    const float* b2   = (const float*)d_in[6];
    const float* lw   = (const float*)d_in[7];
    const float* lb   = (const float*)d_in[8];
    float* out = (float*)d_out;

    char* ws = (char*)d_ws;
    int*   cnt     = (int*)(ws + 0);                 // 160000 B (memset region)
    int*   bsum    = (int*)(ws + 160000);            // 1024 B
    int*   boff    = (int*)(ws + 161024);            // 1024 B
    int*   rploc   = (int*)(ws + 162048);            // 160768 B (40192 ints)
    float* dinv    = (float*)(ws + 322816);          // 160000 B
    int2*  csr     = (int2*)(ws + 482816);           // 5120000 B
    u16*   wswz1   = (u16*)(ws + 5602816);           // 32768 B
    u16*   wswz2   = (u16*)(ws + 5635584);           // 32768 B
    float* partial = (float*)(ws + 5668352);         // 524288 B
    u16*   bufA    = (u16*)(ws + 6192640);           // 10240000 B
    u16*   bufB    = (u16*)(ws + 16432640);          // 10240000 B (total ~26.7 MB)

    const int* src = eidx;             // edge_index[0]
    const int* dst = eidx + N_EDGES;   // edge_index[1]

    hipMemsetAsync(d_ws, 0, 160000, stream);
    k_degree<<<2500, 256, 0, stream>>>(dst, cnt);
    k_wprep<<<128, 256, 0, stream>>>(W1, W2, wswz1, wswz2);
    k_scan1<<<157, 256, 0, stream>>>(cnt, dinv, rploc, bsum);
    k_scan2<<<1, 256, 0, stream>>>(bsum, boff);
    k_fill<<<2500, 256, 0, stream>>>(src, dst, rploc, boff, cnt, dinv, csr);

    k_gemm<true><<<625, 256, 0, stream>>>(x, wswz1, bufA);              // xw1 (bf16)
    k_agg<<<10000, 256, 0, stream>>>(bufA, dinv, rploc, boff, csr, b1, bufB);
    k_gemm<false><<<625, 256, 0, stream>>>(bufB, wswz2, bufA);          // h1@W2 (bf16)
    k_agg<<<10000, 256, 0, stream>>>(bufA, dinv, rploc, boff, csr, b2, bufB);
    k_pool1<<<NGRAPH * NSPLIT, 256, 0, stream>>>(bufB, batch, partial);
    k_pool2<<<NGRAPH, 128, 0, stream>>>(partial, batch, lw, lb, out);
}

// Round 8
// 242.564 us; speedup vs baseline: 3.0231x; 1.0332x over previous
//
#include <hip/hip_runtime.h>
#include <stdint.h>

#define N_NODES 40000
#define N_EDGES 640000
#define HID 128
#define NGRAPH 64
#define NCLASS 10
#define NSPLIT 16

typedef unsigned short u16;
typedef unsigned char u8;
typedef __attribute__((ext_vector_type(8))) short bf16x8;
typedef __attribute__((ext_vector_type(4))) float f32x4;
typedef __attribute__((ext_vector_type(2))) float f32x2;

static __device__ __forceinline__ float bf2f(u16 u) {
    union { uint32_t i; float f; } v; v.i = ((uint32_t)u) << 16; return v.f;
}
static __device__ __forceinline__ u16 f2bf(float f) {
    union { float f; uint32_t i; } v; v.f = f;
    uint32_t u = v.i;
    u = (u + 0x7fff + ((u >> 16) & 1)) >> 16;   // RNE
    return (u16)u;
}

// ---------------- degree histogram over dst ----------------
__global__ void k_degree(const int* __restrict__ dst, int* __restrict__ cnt) {
    int e = blockIdx.x * blockDim.x + threadIdx.x;
    if (e < N_EDGES) atomicAdd(&cnt[dst[e]], 1);
}

// ---------------- scan stage 1: fused dinv + per-block (256) local exclusive scan ----
__launch_bounds__(256)
__global__ void k_scan1(const int* __restrict__ cnt, float* __restrict__ dinv,
                        int* __restrict__ rploc, int* __restrict__ bsum) {
    __shared__ int wsum[4];
    int t = threadIdx.x;
    int idx = blockIdx.x * 256 + t;           // grid 157 -> idx < 40192
    int v = (idx < N_NODES) ? cnt[idx] : 0;
    if (idx < N_NODES) dinv[idx] = rsqrtf((float)(v + 1));   // +1 self-loop
    int lane = t & 63, wv = t >> 6;
    int x = v;
    #pragma unroll
    for (int d = 1; d < 64; d <<= 1) {
        int y = __shfl_up(x, d, 64);
        if (lane >= d) x += y;
    }
    if (lane == 63) wsum[wv] = x;
    __syncthreads();
    int off = 0;
    #pragma unroll
    for (int w = 0; w < 4; ++w) { int s = wsum[w]; if (w < wv) off += s; }
    rploc[idx] = off + x - v;                 // local exclusive
    if (t == 255) bsum[blockIdx.x] = off + x; // block total
}

// ---------------- scan stage 2: exclusive scan of 157 block sums -> boff ----------------
__launch_bounds__(256)
__global__ void k_scan2(const int* __restrict__ bsum, int* __restrict__ boff) {
    __shared__ int wsum[4];
    int t = threadIdx.x;
    int v = (t < 157) ? bsum[t] : 0;
    int lane = t & 63, wv = t >> 6;
    int x = v;
    #pragma unroll
    for (int d = 1; d < 64; d <<= 1) {
        int y = __shfl_up(x, d, 64);
        if (lane >= d) x += y;
    }
    if (lane == 63) wsum[wv] = x;
    __syncthreads();
    int off = 0;
    #pragma unroll
    for (int w = 0; w < 4; ++w) { int s = wsum[w]; if (w < wv) off += s; }
    if (t < 157) boff[t] = off + x - v;
}

// ---------------- CSR fill: slot via count-down on cnt (cursor-free); (src,w) packed ----
__global__ void k_fill(const int* __restrict__ srcs, const int* __restrict__ dsts,
                       const int* __restrict__ rploc, const int* __restrict__ boff,
                       int* __restrict__ cnt, const float* __restrict__ dinv,
                       int2* __restrict__ csr) {
    int e = blockIdx.x * blockDim.x + threadIdx.x;
    if (e < N_EDGES) {
        int s = srcs[e], d = dsts[e];
        int old = atomicSub(&cnt[d], 1);                 // old in [1, deg]
        int p = rploc[d] + boff[d >> 8] + old - 1;
        float w = dinv[s] * dinv[d];
        csr[p] = make_int2(s, __float_as_int(w));
    }
}

// ---------------- W pre-swizzle: fp32 W1,W2 -> bf16 in B-fragment order ----------------
__launch_bounds__(256)
__global__ void k_wprep(const float* __restrict__ W1, const float* __restrict__ W2,
                        u16* __restrict__ wswz1, u16* __restrict__ wswz2) {
    int gid = blockIdx.x * 256 + threadIdx.x;     // grid 128 -> 32768 threads
    int idx = gid & 16383;
    const float* W = (gid < 16384) ? W1 : W2;
    u16* o = (gid < 16384) ? wswz1 : wswz2;
    int j = idx & 7;
    int frag = idx >> 3;
    int l = frag & 63;
    int ks = (frag >> 6) & 3;
    int nt = frag >> 8;
    int k = ks * 32 + (l >> 4) * 8 + j;
    int n = nt * 16 + (l & 15);
    o[idx] = f2bf(W[k * HID + n]);
}

// ---------------- bf16 MFMA GEMM: Out(fp8)[40000,128] = A @ W, W pre-swizzled bf16 ----
// Epilogue quantizes to fp8 e4m3 (hw cvt) — the gather kernel reads half the bytes.
template<bool A_IS_F32>
__launch_bounds__(256)
__global__ void k_gemm(const void* __restrict__ Ap, const u16* __restrict__ wswz,
                       u8* __restrict__ Out) {
    __shared__ u16 wlds[32 * 64 * 8];   // 32 KB
    int t = threadIdx.x;
    {   // vectorized stage: 2048 uint4 / 256 thr = 8 iters
        const uint4* s4 = (const uint4*)wswz;
        uint4* d4 = (uint4*)wlds;
        #pragma unroll
        for (int i = 0; i < 8; ++i) d4[t + 256 * i] = s4[t + 256 * i];
    }
    __syncthreads();

    int lane = t & 63, wv = t >> 6;
    int quad = lane >> 4, m15 = lane & 15;
    int strip = blockIdx.x * 4 + wv;        // 625 blocks x 4 waves = 2500 strips
    int m0 = strip * 16;

    bf16x8 af[4];
    if (A_IS_F32) {
        const float* arow = (const float*)Ap + (size_t)(m0 + m15) * HID;
        #pragma unroll
        for (int ks = 0; ks < 4; ++ks) {
            float4 u = *(const float4*)(arow + ks * 32 + quad * 8);
            float4 v = *(const float4*)(arow + ks * 32 + quad * 8 + 4);
            bf16x8 f;
            f[0] = (short)f2bf(u.x); f[1] = (short)f2bf(u.y);
            f[2] = (short)f2bf(u.z); f[3] = (short)f2bf(u.w);
            f[4] = (short)f2bf(v.x); f[5] = (short)f2bf(v.y);
            f[6] = (short)f2bf(v.z); f[7] = (short)f2bf(v.w);
            af[ks] = f;
        }
    } else {
        const u16* arow = (const u16*)Ap + (size_t)(m0 + m15) * HID;
        #pragma unroll
        for (int ks = 0; ks < 4; ++ks)
            af[ks] = *(const bf16x8*)(arow + ks * 32 + quad * 8);
    }

    #pragma unroll
    for (int nt = 0; nt < 8; ++nt) {
        f32x4 acc = {0.f, 0.f, 0.f, 0.f};
        #pragma unroll
        for (int ks = 0; ks < 4; ++ks) {
            bf16x8 bfr = *(const bf16x8*)(&wlds[((nt * 4 + ks) * 64 + lane) * 8]);
            acc = __builtin_amdgcn_mfma_f32_16x16x32_bf16(af[ks], bfr, acc, 0, 0, 0);
        }
        #pragma unroll
        for (int r = 0; r < 4; ++r) {
            int pk = __builtin_amdgcn_cvt_pk_fp8_f32(acc[r], acc[r], 0, false);
            Out[(size_t)(m0 + quad * 4 + r) * HID + nt * 16 + m15] = (u8)pk;
        }
    }
}

// ---------------- aggregation: out[i] = relu(dinv_i^2*y[i] + sum_e w_e*y[src_e] + b)
// in = fp8 e4m3 rows (128 B); lane reads feats (2*lane, 2*lane+1) as one ushort.
__launch_bounds__(256, 4)
__global__ void k_agg(const u8* __restrict__ in, const float* __restrict__ dinv,
                      const int* __restrict__ rploc, const int* __restrict__ boff,
                      const int2* __restrict__ csr, const float* __restrict__ bias,
                      u16* __restrict__ out) {
    int wid = (blockIdx.x * blockDim.x + threadIdx.x) >> 6;   // one wave per node
    int lane = threadIdx.x & 63;
    if (wid >= N_NODES) return;
    int i = wid;
    float di = dinv[i];
    u16 ps = *(const u16*)(in + (size_t)i * HID + lane * 2);
    f32x2 sf = __builtin_amdgcn_cvt_pk_f32_fp8((int)ps, false);
    float a0 = sf[0] * di * di;
    float a1 = sf[1] * di * di;

    int e  = rploc[i] + boff[i >> 8];
    int e1 = rploc[i + 1] + boff[(i + 1) >> 8];
    for (; e + 8 <= e1; e += 8) {
        int2 c[8];
        u16 p[8];
        #pragma unroll
        for (int u = 0; u < 8; ++u) c[u] = csr[e + u];
        #pragma unroll
        for (int u = 0; u < 8; ++u)
            p[u] = *(const u16*)(in + (size_t)c[u].x * HID + lane * 2);
        #pragma unroll
        for (int u = 0; u < 8; ++u) {
            float w = __int_as_float(c[u].y);
            f32x2 f = __builtin_amdgcn_cvt_pk_f32_fp8((int)p[u], false);
            a0 += w * f[0];
            a1 += w * f[1];
        }
    }
    for (; e < e1; ++e) {
        int2 c = csr[e];
        float w = __int_as_float(c.y);
        u16 p = *(const u16*)(in + (size_t)c.x * HID + lane * 2);
        f32x2 f = __builtin_amdgcn_cvt_pk_f32_fp8((int)p, false);
        a0 += w * f[0];
        a1 += w * f[1];
    }
    a0 = fmaxf(a0 + bias[lane * 2], 0.f);
    a1 = fmaxf(a1 + bias[lane * 2 + 1], 0.f);
    uint32_t o = (uint32_t)f2bf(a0) | ((uint32_t)f2bf(a1) << 16);
    *(uint32_t*)(out + (size_t)i * HID + lane * 2) = o;
}

// ---------------- pool stage 1: 64 graphs x 16 splits, partial sums (no atomics) ----
__launch_bounds__(256)
__global__ void k_pool1(const u16* __restrict__ h, const int* __restrict__ batch,
                        float* __restrict__ partial) {
    __shared__ float red[HID];
    int g = blockIdx.x >> 4;           // / NSPLIT
    int s = blockIdx.x & (NSPLIT - 1);
    int t = threadIdx.x;               // 256 thr: ty = row parity, tf = feature
    int ty = t >> 7, tf = t & 127;
    int lo = 0, n = N_NODES;
    while (n > 0) { int half = n >> 1; int mid = lo + half;
        if (batch[mid] < g) { lo = mid + 1; n -= half + 1; } else n = half; }
    int hi = lo, n2 = N_NODES - lo;
    while (n2 > 0) { int half = n2 >> 1; int mid = hi + half;
        if (batch[mid] < g + 1) { hi = mid + 1; n2 -= half + 1; } else n2 = half; }
    int len = (hi - lo + NSPLIT - 1) / NSPLIT;
    int r0 = lo + s * len;
    int r1 = min(r0 + len, hi);
    float acc = 0.f;
    for (int r = r0 + ty; r < r1; r += 2)
        acc += bf2f(h[(size_t)r * HID + tf]);
    if (ty == 1) red[tf] = acc;
    __syncthreads();
    if (ty == 0) partial[(size_t)blockIdx.x * HID + tf] = acc + red[tf];
}

// ---------------- pool stage 2: reduce 16 partials, mean, fused linear ----------------
__launch_bounds__(128)
__global__ void k_pool2(const float* __restrict__ partial, const int* __restrict__ batch,
                        const float* __restrict__ lin_w, const float* __restrict__ lin_b,
                        float* __restrict__ outp) {
    __shared__ float sh[HID];
    int g = blockIdx.x;
    int t = threadIdx.x;   // 128 threads, thread = feature
    int lo = 0, n = N_NODES;
    while (n > 0) { int half = n >> 1; int mid = lo + half;
        if (batch[mid] < g) { lo = mid + 1; n -= half + 1; } else n = half; }
    int hi = lo, n2 = N_NODES - lo;
    while (n2 > 0) { int half = n2 >> 1; int mid = hi + half;
        if (batch[mid] < g + 1) { hi = mid + 1; n2 -= half + 1; } else n2 = half; }
    float acc = 0.f;
    #pragma unroll
    for (int s = 0; s < NSPLIT; ++s)
        acc += partial[(size_t)(g * NSPLIT + s) * HID + t];
    float c = fmaxf((float)(hi - lo), 1.f);
    sh[t] = acc / c;
    __syncthreads();
    if (t < NCLASS) {
        float a = lin_b[t];
        #pragma unroll 8
        for (int f = 0; f < HID; ++f)
            a += sh[f] * lin_w[f * NCLASS + t];
        outp[g * NCLASS + t] = a;
    }
}

extern "C" void kernel_launch(void* const* d_in, const int* in_sizes, int n_in,
                              void* d_out, int out_size, void* d_ws, size_t ws_size,
                              hipStream_t stream) {
    const float* x    = (const float*)d_in[0];
    const int* eidx   = (const int*)d_in[1];
    const int* batch  = (const int*)d_in[2];
    const float* W1   = (const float*)d_in[3];
    const float* b1   = (const float*)d_in[4];
    const float* W2   = (const float*)d_in[5];
    const float* b2   = (const float*)d_in[6];
    const float* lw   = (const float*)d_in[7];
    const float* lb   = (const float*)d_in[8];
    float* out = (float*)d_out;

    char* ws = (char*)d_ws;
    int*   cnt     = (int*)(ws + 0);                 // 160000 B (memset region)
    int*   bsum    = (int*)(ws + 160000);            // 1024 B
    int*   boff    = (int*)(ws + 161024);            // 1024 B
    int*   rploc   = (int*)(ws + 162048);            // 160768 B (40192 ints)
    float* dinv    = (float*)(ws + 322816);          // 160000 B
    int2*  csr     = (int2*)(ws + 482816);           // 5120000 B
    u16*   wswz1   = (u16*)(ws + 5602816);           // 32768 B
    u16*   wswz2   = (u16*)(ws + 5635584);           // 32768 B
    float* partial = (float*)(ws + 5668352);         // 524288 B
    u8*    bufA8   = (u8*)(ws + 6192640);            // 5120000 B (fp8 rows, gather operand)
    u16*   bufB    = (u16*)(ws + 11312640);          // 10240000 B (bf16 rows)

    const int* src = eidx;             // edge_index[0]
    const int* dst = eidx + N_EDGES;   // edge_index[1]

    hipMemsetAsync(d_ws, 0, 160000, stream);
    k_degree<<<2500, 256, 0, stream>>>(dst, cnt);
    k_wprep<<<128, 256, 0, stream>>>(W1, W2, wswz1, wswz2);
    k_scan1<<<157, 256, 0, stream>>>(cnt, dinv, rploc, bsum);
    k_scan2<<<1, 256, 0, stream>>>(bsum, boff);
    k_fill<<<2500, 256, 0, stream>>>(src, dst, rploc, boff, cnt, dinv, csr);

    k_gemm<true><<<625, 256, 0, stream>>>(x, wswz1, bufA8);             // xw1 (fp8)
    k_agg<<<10000, 256, 0, stream>>>(bufA8, dinv, rploc, boff, csr, b1, bufB);
    k_gemm<false><<<625, 256, 0, stream>>>(bufB, wswz2, bufA8);         // h1@W2 (fp8)
    k_agg<<<10000, 256, 0, stream>>>(bufA8, dinv, rploc, boff, csr, b2, bufB);
    k_pool1<<<NGRAPH * NSPLIT, 256, 0, stream>>>(bufB, batch, partial);
    k_pool2<<<NGRAPH, 128, 0, stream>>>(partial, batch, lw, lb, out);
}

// Round 9
// 227.255 us; speedup vs baseline: 3.2267x; 1.0674x over previous
//
#include <hip/hip_runtime.h>
#include <stdint.h>

#define N_NODES 40000
#define N_EDGES 640000
#define HID 128
#define NGRAPH 64
#define NCLASS 10
#define NSPLIT 16

typedef unsigned short u16;
typedef unsigned char u8;
typedef __attribute__((ext_vector_type(8))) short bf16x8;
typedef __attribute__((ext_vector_type(4))) float f32x4;
typedef __attribute__((ext_vector_type(2))) float f32x2;

static __device__ __forceinline__ float bf2f(u16 u) {
    union { uint32_t i; float f; } v; v.i = ((uint32_t)u) << 16; return v.f;
}
static __device__ __forceinline__ u16 f2bf(float f) {
    union { float f; uint32_t i; } v; v.f = f;
    uint32_t u = v.i;
    u = (u + 0x7fff + ((u >> 16) & 1)) >> 16;   // RNE
    return (u16)u;
}

// ---------------- degree histogram over dst ----------------
__global__ void k_degree(const int* __restrict__ dst, int* __restrict__ cnt) {
    int e = blockIdx.x * blockDim.x + threadIdx.x;
    if (e < N_EDGES) atomicAdd(&cnt[dst[e]], 1);
}

// ---------------- scan stage 1: fused dinv + per-block (256) local exclusive scan ----
__launch_bounds__(256)
__global__ void k_scan1(const int* __restrict__ cnt, float* __restrict__ dinv,
                        int* __restrict__ rploc, int* __restrict__ bsum) {
    __shared__ int wsum[4];
    int t = threadIdx.x;
    int idx = blockIdx.x * 256 + t;           // grid 157 -> idx < 40192
    int v = (idx < N_NODES) ? cnt[idx] : 0;
    if (idx < N_NODES) dinv[idx] = rsqrtf((float)(v + 1));   // +1 self-loop
    int lane = t & 63, wv = t >> 6;
    int x = v;
    #pragma unroll
    for (int d = 1; d < 64; d <<= 1) {
        int y = __shfl_up(x, d, 64);
        if (lane >= d) x += y;
    }
    if (lane == 63) wsum[wv] = x;
    __syncthreads();
    int off = 0;
    #pragma unroll
    for (int w = 0; w < 4; ++w) { int s = wsum[w]; if (w < wv) off += s; }
    rploc[idx] = off + x - v;                 // local exclusive
    if (t == 255) bsum[blockIdx.x] = off + x; // block total
}

// ---------------- scan stage 2: exclusive scan of 157 block sums -> boff ----------------
__launch_bounds__(256)
__global__ void k_scan2(const int* __restrict__ bsum, int* __restrict__ boff) {
    __shared__ int wsum[4];
    int t = threadIdx.x;
    int v = (t < 157) ? bsum[t] : 0;
    int lane = t & 63, wv = t >> 6;
    int x = v;
    #pragma unroll
    for (int d = 1; d < 64; d <<= 1) {
        int y = __shfl_up(x, d, 64);
        if (lane >= d) x += y;
    }
    if (lane == 63) wsum[wv] = x;
    __syncthreads();
    int off = 0;
    #pragma unroll
    for (int w = 0; w < 4; ++w) { int s = wsum[w]; if (w < wv) off += s; }
    if (t < 157) boff[t] = off + x - v;
}

// ---------------- CSR fill: slot via count-down on cnt (cursor-free); (src,w) packed ----
__global__ void k_fill(const int* __restrict__ srcs, const int* __restrict__ dsts,
                       const int* __restrict__ rploc, const int* __restrict__ boff,
                       int* __restrict__ cnt, const float* __restrict__ dinv,
                       int2* __restrict__ csr) {
    int e = blockIdx.x * blockDim.x + threadIdx.x;
    if (e < N_EDGES) {
        int s = srcs[e], d = dsts[e];
        int old = atomicSub(&cnt[d], 1);                 // old in [1, deg]
        int p = rploc[d] + boff[d >> 8] + old - 1;
        float w = dinv[s] * dinv[d];
        csr[p] = make_int2(s, __float_as_int(w));
    }
}

// ---------------- W pre-swizzle: fp32 W1,W2 -> bf16 in B-fragment order ----------------
__launch_bounds__(256)
__global__ void k_wprep(const float* __restrict__ W1, const float* __restrict__ W2,
                        u16* __restrict__ wswz1, u16* __restrict__ wswz2) {
    int gid = blockIdx.x * 256 + threadIdx.x;     // grid 128 -> 32768 threads
    int idx = gid & 16383;
    const float* W = (gid < 16384) ? W1 : W2;
    u16* o = (gid < 16384) ? wswz1 : wswz2;
    int j = idx & 7;
    int frag = idx >> 3;
    int l = frag & 63;
    int ks = (frag >> 6) & 3;
    int nt = frag >> 8;
    int k = ks * 32 + (l >> 4) * 8 + j;
    int n = nt * 16 + (l & 15);
    o[idx] = f2bf(W[k * HID + n]);
}

// ---------------- bf16 MFMA GEMM: Out(fp8)[40000,128] = A @ W, W pre-swizzled bf16 ----
template<bool A_IS_F32>
__launch_bounds__(256)
__global__ void k_gemm(const void* __restrict__ Ap, const u16* __restrict__ wswz,
                       u8* __restrict__ Out) {
    __shared__ u16 wlds[32 * 64 * 8];   // 32 KB
    int t = threadIdx.x;
    {   // vectorized stage: 2048 uint4 / 256 thr = 8 iters
        const uint4* s4 = (const uint4*)wswz;
        uint4* d4 = (uint4*)wlds;
        #pragma unroll
        for (int i = 0; i < 8; ++i) d4[t + 256 * i] = s4[t + 256 * i];
    }
    __syncthreads();

    int lane = t & 63, wv = t >> 6;
    int quad = lane >> 4, m15 = lane & 15;
    int strip = blockIdx.x * 4 + wv;        // 625 blocks x 4 waves = 2500 strips
    int m0 = strip * 16;

    bf16x8 af[4];
    if (A_IS_F32) {
        const float* arow = (const float*)Ap + (size_t)(m0 + m15) * HID;
        #pragma unroll
        for (int ks = 0; ks < 4; ++ks) {
            float4 u = *(const float4*)(arow + ks * 32 + quad * 8);
            float4 v = *(const float4*)(arow + ks * 32 + quad * 8 + 4);
            bf16x8 f;
            f[0] = (short)f2bf(u.x); f[1] = (short)f2bf(u.y);
            f[2] = (short)f2bf(u.z); f[3] = (short)f2bf(u.w);
            f[4] = (short)f2bf(v.x); f[5] = (short)f2bf(v.y);
            f[6] = (short)f2bf(v.z); f[7] = (short)f2bf(v.w);
            af[ks] = f;
        }
    } else {
        const u16* arow = (const u16*)Ap + (size_t)(m0 + m15) * HID;
        #pragma unroll
        for (int ks = 0; ks < 4; ++ks)
            af[ks] = *(const bf16x8*)(arow + ks * 32 + quad * 8);
    }

    #pragma unroll
    for (int nt = 0; nt < 8; ++nt) {
        f32x4 acc = {0.f, 0.f, 0.f, 0.f};
        #pragma unroll
        for (int ks = 0; ks < 4; ++ks) {
            bf16x8 bfr = *(const bf16x8*)(&wlds[((nt * 4 + ks) * 64 + lane) * 8]);
            acc = __builtin_amdgcn_mfma_f32_16x16x32_bf16(af[ks], bfr, acc, 0, 0, 0);
        }
        #pragma unroll
        for (int r = 0; r < 4; ++r) {
            int pk = __builtin_amdgcn_cvt_pk_fp8_f32(acc[r], acc[r], 0, false);
            Out[(size_t)(m0 + quad * 4 + r) * HID + nt * 16 + m15] = (u8)pk;
        }
    }
}

// ---------------- aggregation: out[i] = relu(dinv_i^2*y[i] + sum_e w_e*y[src_e] + b)
// fp8 rows; TWO nodes per wave (32 lanes each, 4 feats/lane) -> 2x edge streams,
// 8 waves/EU -> ~4x more outstanding gathers than round 7.
__launch_bounds__(256, 8)
__global__ void k_agg(const u8* __restrict__ in, const float* __restrict__ dinv,
                      const int* __restrict__ rploc, const int* __restrict__ boff,
                      const int2* __restrict__ csr, const float* __restrict__ bias,
                      u16* __restrict__ out) {
    int wid = (blockIdx.x * blockDim.x + threadIdx.x) >> 6;   // 2 nodes per wave
    int lane = threadIdx.x & 63;
    int half = lane >> 5, sub = lane & 31;
    int i = wid * 2 + half;                                   // N even -> always < N
    if (i >= N_NODES) return;
    float di = dinv[i];
    uint32_t ps = *(const uint32_t*)(in + (size_t)i * HID + sub * 4);
    f32x2 s01 = __builtin_amdgcn_cvt_pk_f32_fp8((int)ps, false);
    f32x2 s23 = __builtin_amdgcn_cvt_pk_f32_fp8((int)ps, true);
    float a0 = s01[0] * di * di, a1 = s01[1] * di * di;
    float a2 = s23[0] * di * di, a3 = s23[1] * di * di;

    int e  = rploc[i] + boff[i >> 8];
    int e1 = rploc[i + 1] + boff[(i + 1) >> 8];
    int deg = e1 - e;
    for (int k = 0; k < deg; k += 8) {
        int2 c[8];
        uint32_t p[8];
        #pragma unroll
        for (int u = 0; u < 8; ++u) {
            int idx = e + k + u;
            c[u] = csr[idx < e1 ? idx : e];        // clamp; csr padded by 1 entry
        }
        #pragma unroll
        for (int u = 0; u < 8; ++u)
            p[u] = *(const uint32_t*)(in + (size_t)c[u].x * HID + sub * 4);
        #pragma unroll
        for (int u = 0; u < 8; ++u) {
            float w = (k + u < deg) ? __int_as_float(c[u].y) : 0.f;
            f32x2 f01 = __builtin_amdgcn_cvt_pk_f32_fp8((int)p[u], false);
            f32x2 f23 = __builtin_amdgcn_cvt_pk_f32_fp8((int)p[u], true);
            a0 += w * f01[0];  a1 += w * f01[1];
            a2 += w * f23[0];  a3 += w * f23[1];
        }
    }
    float4 bv = *(const float4*)(bias + sub * 4);
    a0 = fmaxf(a0 + bv.x, 0.f);
    a1 = fmaxf(a1 + bv.y, 0.f);
    a2 = fmaxf(a2 + bv.z, 0.f);
    a3 = fmaxf(a3 + bv.w, 0.f);
    uint32_t lo = (uint32_t)f2bf(a0) | ((uint32_t)f2bf(a1) << 16);
    uint32_t hi = (uint32_t)f2bf(a2) | ((uint32_t)f2bf(a3) << 16);
    *(uint2*)(out + (size_t)i * HID + sub * 4) = make_uint2(lo, hi);
}

// ---------------- pool stage 1: 64 graphs x 16 splits, partial sums (no atomics) ----
__launch_bounds__(256)
__global__ void k_pool1(const u16* __restrict__ h, const int* __restrict__ batch,
                        float* __restrict__ partial) {
    __shared__ float red[HID];
    int g = blockIdx.x >> 4;           // / NSPLIT
    int s = blockIdx.x & (NSPLIT - 1);
    int t = threadIdx.x;               // 256 thr: ty = row parity, tf = feature
    int ty = t >> 7, tf = t & 127;
    int lo = 0, n = N_NODES;
    while (n > 0) { int half = n >> 1; int mid = lo + half;
        if (batch[mid] < g) { lo = mid + 1; n -= half + 1; } else n = half; }
    int hi = lo, n2 = N_NODES - lo;
    while (n2 > 0) { int half = n2 >> 1; int mid = hi + half;
        if (batch[mid] < g + 1) { hi = mid + 1; n2 -= half + 1; } else n2 = half; }
    int len = (hi - lo + NSPLIT - 1) / NSPLIT;
    int r0 = lo + s * len;
    int r1 = min(r0 + len, hi);
    float acc = 0.f;
    for (int r = r0 + ty; r < r1; r += 2)
        acc += bf2f(h[(size_t)r * HID + tf]);
    if (ty == 1) red[tf] = acc;
    __syncthreads();
    if (ty == 0) partial[(size_t)blockIdx.x * HID + tf] = acc + red[tf];
}

// ---------------- pool stage 2: reduce 16 partials, mean, fused linear ----------------
__launch_bounds__(128)
__global__ void k_pool2(const float* __restrict__ partial, const int* __restrict__ batch,
                        const float* __restrict__ lin_w, const float* __restrict__ lin_b,
                        float* __restrict__ outp) {
    __shared__ float sh[HID];
    int g = blockIdx.x;
    int t = threadIdx.x;   // 128 threads, thread = feature
    int lo = 0, n = N_NODES;
    while (n > 0) { int half = n >> 1; int mid = lo + half;
        if (batch[mid] < g) { lo = mid + 1; n -= half + 1; } else n = half; }
    int hi = lo, n2 = N_NODES - lo;
    while (n2 > 0) { int half = n2 >> 1; int mid = hi + half;
        if (batch[mid] < g + 1) { hi = mid + 1; n2 -= half + 1; } else n2 = half; }
    float acc = 0.f;
    #pragma unroll
    for (int s = 0; s < NSPLIT; ++s)
        acc += partial[(size_t)(g * NSPLIT + s) * HID + t];
    float c = fmaxf((float)(hi - lo), 1.f);
    sh[t] = acc / c;
    __syncthreads();
    if (t < NCLASS) {
        float a = lin_b[t];
        #pragma unroll 8
        for (int f = 0; f < HID; ++f)
            a += sh[f] * lin_w[f * NCLASS + t];
        outp[g * NCLASS + t] = a;
    }
}

extern "C" void kernel_launch(void* const* d_in, const int* in_sizes, int n_in,
                              void* d_out, int out_size, void* d_ws, size_t ws_size,
                              hipStream_t stream) {
    const float* x    = (const float*)d_in[0];
    const int* eidx   = (const int*)d_in[1];
    const int* batch  = (const int*)d_in[2];
    const float* W1   = (const float*)d_in[3];
    const float* b1   = (const float*)d_in[4];
    const float* W2   = (const float*)d_in[5];
    const float* b2   = (const float*)d_in[6];
    const float* lw   = (const float*)d_in[7];
    const float* lb   = (const float*)d_in[8];
    float* out = (float*)d_out;

    char* ws = (char*)d_ws;
    int*   cnt     = (int*)(ws + 0);                 // 160000 B (memset region)
    int*   bsum    = (int*)(ws + 160000);            // 1024 B
    int*   boff    = (int*)(ws + 161024);            // 1024 B
    int*   rploc   = (int*)(ws + 162048);            // 160768 B (40192 ints)
    float* dinv    = (float*)(ws + 322816);          // 160000 B
    int2*  csr     = (int2*)(ws + 482816);           // 5120000 B + 16 B pad
    u16*   wswz1   = (u16*)(ws + 5602832);           // 32768 B
    u16*   wswz2   = (u16*)(ws + 5635600);           // 32768 B
    float* partial = (float*)(ws + 5668368);         // 524288 B
    u8*    bufA8   = (u8*)(ws + 6192656);            // 5120000 B (fp8 rows, gather operand)
    u16*   bufB    = (u16*)(ws + 11312656);          // 10240000 B (bf16 rows)

    const int* src = eidx;             // edge_index[0]
    const int* dst = eidx + N_EDGES;   // edge_index[1]

    hipMemsetAsync(d_ws, 0, 160000, stream);
    k_degree<<<2500, 256, 0, stream>>>(dst, cnt);
    k_wprep<<<128, 256, 0, stream>>>(W1, W2, wswz1, wswz2);
    k_scan1<<<157, 256, 0, stream>>>(cnt, dinv, rploc, bsum);
    k_scan2<<<1, 256, 0, stream>>>(bsum, boff);
    k_fill<<<2500, 256, 0, stream>>>(src, dst, rploc, boff, cnt, dinv, csr);

    k_gemm<true><<<625, 256, 0, stream>>>(x, wswz1, bufA8);             // xw1 (fp8)
    k_agg<<<5000, 256, 0, stream>>>(bufA8, dinv, rploc, boff, csr, b1, bufB);
    k_gemm<false><<<625, 256, 0, stream>>>(bufB, wswz2, bufA8);         // h1@W2 (fp8)
    k_agg<<<5000, 256, 0, stream>>>(bufA8, dinv, rploc, boff, csr, b2, bufB);
    k_pool1<<<NGRAPH * NSPLIT, 256, 0, stream>>>(bufB, batch, partial);
    k_pool2<<<NGRAPH, 128, 0, stream>>>(partial, batch, lw, lb, out);
}

// Round 10
// 221.187 us; speedup vs baseline: 3.3153x; 1.0274x over previous
//
#include <hip/hip_runtime.h>
#include <stdint.h>

#define N_NODES 40000
#define N_EDGES 640000
#define HID 128
#define NGRAPH 64
#define NCLASS 10
#define NSPLIT 16

typedef unsigned short u16;
typedef unsigned char u8;
typedef __attribute__((ext_vector_type(8))) short bf16x8;
typedef __attribute__((ext_vector_type(4))) float f32x4;
typedef __attribute__((ext_vector_type(2))) float f32x2;

static __device__ __forceinline__ float bf2f(u16 u) {
    union { uint32_t i; float f; } v; v.i = ((uint32_t)u) << 16; return v.f;
}
static __device__ __forceinline__ u16 f2bf(float f) {
    union { float f; uint32_t i; } v; v.f = f;
    uint32_t u = v.i;
    u = (u + 0x7fff + ((u >> 16) & 1)) >> 16;   // RNE
    return (u16)u;
}

// ---------------- degree histogram over dst ----------------
__global__ void k_degree(const int* __restrict__ dst, int* __restrict__ cnt) {
    int e = blockIdx.x * blockDim.x + threadIdx.x;
    if (e < N_EDGES) atomicAdd(&cnt[dst[e]], 1);
}

// ---------------- scan stage 1: fused dinv + per-block (256) local exclusive scan ----
__launch_bounds__(256)
__global__ void k_scan1(const int* __restrict__ cnt, float* __restrict__ dinv,
                        int* __restrict__ rploc, int* __restrict__ bsum) {
    __shared__ int wsum[4];
    int t = threadIdx.x;
    int idx = blockIdx.x * 256 + t;           // grid 157 -> idx < 40192
    int v = (idx < N_NODES) ? cnt[idx] : 0;
    if (idx < N_NODES) dinv[idx] = rsqrtf((float)(v + 1));   // +1 self-loop
    int lane = t & 63, wv = t >> 6;
    int x = v;
    #pragma unroll
    for (int d = 1; d < 64; d <<= 1) {
        int y = __shfl_up(x, d, 64);
        if (lane >= d) x += y;
    }
    if (lane == 63) wsum[wv] = x;
    __syncthreads();
    int off = 0;
    #pragma unroll
    for (int w = 0; w < 4; ++w) { int s = wsum[w]; if (w < wv) off += s; }
    rploc[idx] = off + x - v;                 // local exclusive
    if (t == 255) bsum[blockIdx.x] = off + x; // block total
}

// ---------------- scan stage 2: exclusive scan of 157 block sums -> boff ----------------
__launch_bounds__(256)
__global__ void k_scan2(const int* __restrict__ bsum, int* __restrict__ boff) {
    __shared__ int wsum[4];
    int t = threadIdx.x;
    int v = (t < 157) ? bsum[t] : 0;
    int lane = t & 63, wv = t >> 6;
    int x = v;
    #pragma unroll
    for (int d = 1; d < 64; d <<= 1) {
        int y = __shfl_up(x, d, 64);
        if (lane >= d) x += y;
    }
    if (lane == 63) wsum[wv] = x;
    __syncthreads();
    int off = 0;
    #pragma unroll
    for (int w = 0; w < 4; ++w) { int s = wsum[w]; if (w < wv) off += s; }
    if (t < 157) boff[t] = off + x - v;
}

// ---------------- CSR fill: src-only (norm folded into z rows); count-down slots ----
__global__ void k_fill(const int* __restrict__ srcs, const int* __restrict__ dsts,
                       const int* __restrict__ rploc, const int* __restrict__ boff,
                       int* __restrict__ cnt, int* __restrict__ csr) {
    int e = blockIdx.x * blockDim.x + threadIdx.x;
    if (e < N_EDGES) {
        int s = srcs[e], d = dsts[e];
        int old = atomicSub(&cnt[d], 1);                 // old in [1, deg]
        csr[rploc[d] + boff[d >> 8] + old - 1] = s;
    }
}

// ---------------- W pre-swizzle: fp32 W1,W2 -> bf16 in B-fragment order ----------------
__launch_bounds__(256)
__global__ void k_wprep(const float* __restrict__ W1, const float* __restrict__ W2,
                        u16* __restrict__ wswz1, u16* __restrict__ wswz2) {
    int gid = blockIdx.x * 256 + threadIdx.x;     // grid 128 -> 32768 threads
    int idx = gid & 16383;
    const float* W = (gid < 16384) ? W1 : W2;
    u16* o = (gid < 16384) ? wswz1 : wswz2;
    int j = idx & 7;
    int frag = idx >> 3;
    int l = frag & 63;
    int ks = (frag >> 6) & 3;
    int nt = frag >> 8;
    int k = ks * 32 + (l >> 4) * 8 + j;
    int n = nt * 16 + (l & 15);
    o[idx] = f2bf(W[k * HID + n]);
}

// ---------------- bf16 MFMA GEMM: Z(fp8)[40000,128] = dinv_row * (A @ W) ----------------
template<bool A_IS_F32>
__launch_bounds__(256)
__global__ void k_gemm(const void* __restrict__ Ap, const u16* __restrict__ wswz,
                       const float* __restrict__ dinv, u8* __restrict__ Out) {
    __shared__ u16 wlds[32 * 64 * 8];   // 32 KB
    int t = threadIdx.x;
    {   // vectorized stage: 2048 uint4 / 256 thr = 8 iters
        const uint4* s4 = (const uint4*)wswz;
        uint4* d4 = (uint4*)wlds;
        #pragma unroll
        for (int i = 0; i < 8; ++i) d4[t + 256 * i] = s4[t + 256 * i];
    }
    __syncthreads();

    int lane = t & 63, wv = t >> 6;
    int quad = lane >> 4, m15 = lane & 15;
    int strip = blockIdx.x * 4 + wv;        // 625 blocks x 4 waves = 2500 strips
    int m0 = strip * 16;

    bf16x8 af[4];
    if (A_IS_F32) {
        const float* arow = (const float*)Ap + (size_t)(m0 + m15) * HID;
        #pragma unroll
        for (int ks = 0; ks < 4; ++ks) {
            float4 u = *(const float4*)(arow + ks * 32 + quad * 8);
            float4 v = *(const float4*)(arow + ks * 32 + quad * 8 + 4);
            bf16x8 f;
            f[0] = (short)f2bf(u.x); f[1] = (short)f2bf(u.y);
            f[2] = (short)f2bf(u.z); f[3] = (short)f2bf(u.w);
            f[4] = (short)f2bf(v.x); f[5] = (short)f2bf(v.y);
            f[6] = (short)f2bf(v.z); f[7] = (short)f2bf(v.w);
            af[ks] = f;
        }
    } else {
        const u16* arow = (const u16*)Ap + (size_t)(m0 + m15) * HID;
        #pragma unroll
        for (int ks = 0; ks < 4; ++ks)
            af[ks] = *(const bf16x8*)(arow + ks * 32 + quad * 8);
    }

    #pragma unroll
    for (int nt = 0; nt < 8; ++nt) {
        f32x4 acc = {0.f, 0.f, 0.f, 0.f};
        #pragma unroll
        for (int ks = 0; ks < 4; ++ks) {
            bf16x8 bfr = *(const bf16x8*)(&wlds[((nt * 4 + ks) * 64 + lane) * 8]);
            acc = __builtin_amdgcn_mfma_f32_16x16x32_bf16(af[ks], bfr, acc, 0, 0, 0);
        }
        #pragma unroll
        for (int r = 0; r < 4; ++r) {
            float zc = acc[r] * dinv[m0 + quad * 4 + r];
            int pk = __builtin_amdgcn_cvt_pk_fp8_f32(zc, zc, 0, false);
            Out[(size_t)(m0 + quad * 4 + r) * HID + nt * 16 + m15] = (u8)pk;
        }
    }
}

// ---------------- aggregation: h[i] = relu(dinv_i * (z[i] + sum_e z[src_e]) + b)
// fp8 z rows; FOUR nodes per wave (16 lanes x 8 feats = one 128 B row) -> 4 edge
// streams/wave, unroll 8, 8 waves/EU.
__launch_bounds__(256, 8)
__global__ void k_agg(const u8* __restrict__ in, const float* __restrict__ dinv,
                      const int* __restrict__ rploc, const int* __restrict__ boff,
                      const int* __restrict__ csr, const float* __restrict__ bias,
                      u16* __restrict__ out) {
    int wid = (blockIdx.x * blockDim.x + threadIdx.x) >> 6;   // 4 nodes per wave
    int lane = threadIdx.x & 63;
    int q = lane >> 4, sub = lane & 15;
    int i = wid * 4 + q;                                      // 40000 % 4 == 0
    if (i >= N_NODES) return;
    float di = dinv[i];
    const u8* base = in + (size_t)sub * 8;
    uint2 ps = *(const uint2*)(base + (size_t)i * HID);
    f32x2 t0 = __builtin_amdgcn_cvt_pk_f32_fp8((int)ps.x, false);
    f32x2 t1 = __builtin_amdgcn_cvt_pk_f32_fp8((int)ps.x, true);
    f32x2 t2 = __builtin_amdgcn_cvt_pk_f32_fp8((int)ps.y, false);
    f32x2 t3 = __builtin_amdgcn_cvt_pk_f32_fp8((int)ps.y, true);
    float a0 = t0[0], a1 = t0[1], a2 = t1[0], a3 = t1[1];
    float a4 = t2[0], a5 = t2[1], a6 = t3[0], a7 = t3[1];

    int e  = rploc[i] + boff[i >> 8];
    int e1 = rploc[i + 1] + boff[(i + 1) >> 8];
    for (; e + 8 <= e1; e += 8) {
        int s[8];
        uint2 p[8];
        #pragma unroll
        for (int u = 0; u < 8; ++u) s[u] = csr[e + u];
        #pragma unroll
        for (int u = 0; u < 8; ++u)
            p[u] = *(const uint2*)(base + (size_t)s[u] * HID);
        #pragma unroll
        for (int u = 0; u < 8; ++u) {
            f32x2 f01 = __builtin_amdgcn_cvt_pk_f32_fp8((int)p[u].x, false);
            f32x2 f23 = __builtin_amdgcn_cvt_pk_f32_fp8((int)p[u].x, true);
            f32x2 f45 = __builtin_amdgcn_cvt_pk_f32_fp8((int)p[u].y, false);
            f32x2 f67 = __builtin_amdgcn_cvt_pk_f32_fp8((int)p[u].y, true);
            a0 += f01[0]; a1 += f01[1]; a2 += f23[0]; a3 += f23[1];
            a4 += f45[0]; a5 += f45[1]; a6 += f67[0]; a7 += f67[1];
        }
    }
    for (; e < e1; ++e) {
        uint2 p = *(const uint2*)(base + (size_t)csr[e] * HID);
        f32x2 f01 = __builtin_amdgcn_cvt_pk_f32_fp8((int)p.x, false);
        f32x2 f23 = __builtin_amdgcn_cvt_pk_f32_fp8((int)p.x, true);
        f32x2 f45 = __builtin_amdgcn_cvt_pk_f32_fp8((int)p.y, false);
        f32x2 f67 = __builtin_amdgcn_cvt_pk_f32_fp8((int)p.y, true);
        a0 += f01[0]; a1 += f01[1]; a2 += f23[0]; a3 += f23[1];
        a4 += f45[0]; a5 += f45[1]; a6 += f67[0]; a7 += f67[1];
    }
    float4 b0 = *(const float4*)(bias + sub * 8);
    float4 b1 = *(const float4*)(bias + sub * 8 + 4);
    a0 = fmaxf(di * a0 + b0.x, 0.f);  a1 = fmaxf(di * a1 + b0.y, 0.f);
    a2 = fmaxf(di * a2 + b0.z, 0.f);  a3 = fmaxf(di * a3 + b0.w, 0.f);
    a4 = fmaxf(di * a4 + b1.x, 0.f);  a5 = fmaxf(di * a5 + b1.y, 0.f);
    a6 = fmaxf(di * a6 + b1.z, 0.f);  a7 = fmaxf(di * a7 + b1.w, 0.f);
    uint4 o;
    o.x = (uint32_t)f2bf(a0) | ((uint32_t)f2bf(a1) << 16);
    o.y = (uint32_t)f2bf(a2) | ((uint32_t)f2bf(a3) << 16);
    o.z = (uint32_t)f2bf(a4) | ((uint32_t)f2bf(a5) << 16);
    o.w = (uint32_t)f2bf(a6) | ((uint32_t)f2bf(a7) << 16);
    *(uint4*)(out + (size_t)i * HID + sub * 8) = o;
}

// ---------------- pool stage 1: 64 graphs x 16 splits; uint2 loads, LDS reduce ----
__launch_bounds__(256)
__global__ void k_pool1(const u16* __restrict__ h, const int* __restrict__ batch,
                        float* __restrict__ partial) {
    __shared__ float red[8][HID];
    int g = blockIdx.x >> 4;           // / NSPLIT
    int s = blockIdx.x & (NSPLIT - 1);
    int t = threadIdx.x;               // c = uint2 chunk (4 feats), tr = row lane (8 rows)
    int c = t & 31, tr = t >> 5;
    int lo = 0, n = N_NODES;
    while (n > 0) { int half = n >> 1; int mid = lo + half;
        if (batch[mid] < g) { lo = mid + 1; n -= half + 1; } else n = half; }
    int hi = lo, n2 = N_NODES - lo;
    while (n2 > 0) { int half = n2 >> 1; int mid = hi + half;
        if (batch[mid] < g + 1) { hi = mid + 1; n2 -= half + 1; } else n2 = half; }
    int len = (hi - lo + NSPLIT - 1) / NSPLIT;
    int r0 = lo + s * len;
    int r1 = min(r0 + len, hi);
    float a0 = 0.f, a1 = 0.f, a2 = 0.f, a3 = 0.f;
    for (int r = r0 + tr; r < r1; r += 8) {
        uint2 v = *(const uint2*)(h + (size_t)r * HID + c * 4);
        a0 += bf2f((u16)(v.x & 0xffff)); a1 += bf2f((u16)(v.x >> 16));
        a2 += bf2f((u16)(v.y & 0xffff)); a3 += bf2f((u16)(v.y >> 16));
    }
    red[tr][c * 4 + 0] = a0; red[tr][c * 4 + 1] = a1;
    red[tr][c * 4 + 2] = a2; red[tr][c * 4 + 3] = a3;
    __syncthreads();
    if (t < HID) {
        float acc = 0.f;
        #pragma unroll
        for (int j = 0; j < 8; ++j) acc += red[j][t];
        partial[(size_t)blockIdx.x * HID + t] = acc;
    }
}

// ---------------- pool stage 2: reduce 16 partials, mean, fused linear ----------------
__launch_bounds__(128)
__global__ void k_pool2(const float* __restrict__ partial, const int* __restrict__ batch,
                        const float* __restrict__ lin_w, const float* __restrict__ lin_b,
                        float* __restrict__ outp) {
    __shared__ float sh[HID];
    int g = blockIdx.x;
    int t = threadIdx.x;   // 128 threads, thread = feature
    int lo = 0, n = N_NODES;
    while (n > 0) { int half = n >> 1; int mid = lo + half;
        if (batch[mid] < g) { lo = mid + 1; n -= half + 1; } else n = half; }
    int hi = lo, n2 = N_NODES - lo;
    while (n2 > 0) { int half = n2 >> 1; int mid = hi + half;
        if (batch[mid] < g + 1) { hi = mid + 1; n2 -= half + 1; } else n2 = half; }
    float acc = 0.f;
    #pragma unroll
    for (int s = 0; s < NSPLIT; ++s)
        acc += partial[(size_t)(g * NSPLIT + s) * HID + t];
    float c = fmaxf((float)(hi - lo), 1.f);
    sh[t] = acc / c;
    __syncthreads();
    if (t < NCLASS) {
        float a = lin_b[t];
        #pragma unroll 8
        for (int f = 0; f < HID; ++f)
            a += sh[f] * lin_w[f * NCLASS + t];
        outp[g * NCLASS + t] = a;
    }
}

extern "C" void kernel_launch(void* const* d_in, const int* in_sizes, int n_in,
                              void* d_out, int out_size, void* d_ws, size_t ws_size,
                              hipStream_t stream) {
    const float* x    = (const float*)d_in[0];
    const int* eidx   = (const int*)d_in[1];
    const int* batch  = (const int*)d_in[2];
    const float* W1   = (const float*)d_in[3];
    const float* b1   = (const float*)d_in[4];
    const float* W2   = (const float*)d_in[5];
    const float* b2   = (const float*)d_in[6];
    const float* lw   = (const float*)d_in[7];
    const float* lb   = (const float*)d_in[8];
    float* out = (float*)d_out;

    char* ws = (char*)d_ws;
    int*   cnt     = (int*)(ws + 0);                 // 160000 B (memset region)
    int*   bsum    = (int*)(ws + 160000);            // 1024 B
    int*   boff    = (int*)(ws + 161024);            // 1024 B
    int*   rploc   = (int*)(ws + 162048);            // 160768 B (40192 ints)
    float* dinv    = (float*)(ws + 322816);          // 160000 B
    int*   csr     = (int*)(ws + 482816);            // 2560032 B (src only + pad)
    u16*   wswz1   = (u16*)(ws + 3042848);           // 32768 B
    u16*   wswz2   = (u16*)(ws + 3075616);           // 32768 B
    float* partial = (float*)(ws + 3108384);         // 524288 B
    u8*    bufA8   = (u8*)(ws + 3632672);            // 5120000 B (fp8 z rows)
    u16*   bufB    = (u16*)(ws + 8752672);           // 10240000 B (bf16 h rows)

    const int* src = eidx;             // edge_index[0]
    const int* dst = eidx + N_EDGES;   // edge_index[1]

    hipMemsetAsync(d_ws, 0, 160000, stream);
    k_degree<<<2500, 256, 0, stream>>>(dst, cnt);
    k_wprep<<<128, 256, 0, stream>>>(W1, W2, wswz1, wswz2);
    k_scan1<<<157, 256, 0, stream>>>(cnt, dinv, rploc, bsum);
    k_scan2<<<1, 256, 0, stream>>>(bsum, boff);
    k_fill<<<2500, 256, 0, stream>>>(src, dst, rploc, boff, cnt, csr);

    k_gemm<true><<<625, 256, 0, stream>>>(x, wswz1, dinv, bufA8);       // z1 (fp8)
    k_agg<<<2500, 256, 0, stream>>>(bufA8, dinv, rploc, boff, csr, b1, bufB);
    k_gemm<false><<<625, 256, 0, stream>>>(bufB, wswz2, dinv, bufA8);   // z2 (fp8)
    k_agg<<<2500, 256, 0, stream>>>(bufA8, dinv, rploc, boff, csr, b2, bufB);
    k_pool1<<<NGRAPH * NSPLIT, 256, 0, stream>>>(bufB, batch, partial);
    k_pool2<<<NGRAPH, 128, 0, stream>>>(partial, batch, lw, lb, out);
}

// Round 12
// 210.451 us; speedup vs baseline: 3.4844x; 1.0510x over previous
//
#include <hip/hip_runtime.h>
#include <stdint.h>

#define N_NODES 40000
#define N_EDGES 640000
#define HID 128
#define NGRAPH 64
#define NCLASS 10
#define NSPLIT 16
#define NBSUM 157           // ceil(40000/256)

typedef unsigned short u16;
typedef unsigned char u8;
typedef __attribute__((ext_vector_type(8))) short bf16x8;
typedef __attribute__((ext_vector_type(4))) float f32x4;
typedef __attribute__((ext_vector_type(2))) float f32x2;

static __device__ __forceinline__ float bf2f(u16 u) {
    union { uint32_t i; float f; } v; v.i = ((uint32_t)u) << 16; return v.f;
}
static __device__ __forceinline__ u16 f2bf(float f) {
    union { float f; uint32_t i; } v; v.f = f;
    uint32_t u = v.i;
    u = (u + 0x7fff + ((u >> 16) & 1)) >> 16;   // RNE
    return (u16)u;
}

// per-block recompute of boff (exclusive scan of 157 block sums) into LDS.
// cross-dispatch reads of bsum -> no coherence hazard. ~300 cyc per block.
static __device__ __forceinline__ void block_boff(const int* __restrict__ bsum,
                                                  int* sboff, int* wsum) {
    int t = threadIdx.x;
    int v = (t < NBSUM) ? bsum[t] : 0;
    int lane = t & 63, wv = t >> 6;
    int x = v;
    #pragma unroll
    for (int d = 1; d < 64; d <<= 1) {
        int y = __shfl_up(x, d, 64);
        if (lane >= d) x += y;
    }
    if (lane == 63) wsum[wv] = x;
    __syncthreads();
    int off = 0;
    #pragma unroll
    for (int w = 0; w < 4; ++w) { int s = wsum[w]; if (w < wv) off += s; }
    if (t < NBSUM) sboff[t] = off + x - v;
    __syncthreads();
}

// ---------------- k0: degree histogram (blocks 0..2499) ∥ W pre-swizzle (2500..2627) ----
__launch_bounds__(256)
__global__ void k_deg_wprep(const int* __restrict__ dst, int* __restrict__ cnt,
                            const float* __restrict__ W1, const float* __restrict__ W2,
                            u16* __restrict__ wswz1, u16* __restrict__ wswz2) {
    if (blockIdx.x < 2500) {
        int e = blockIdx.x * 256 + threadIdx.x;        // 640000 exact
        atomicAdd(&cnt[dst[e]], 1);
    } else {
        int gid = (blockIdx.x - 2500) * 256 + threadIdx.x;   // [0,32768)
        int idx = gid & 16383;
        const float* W = (gid < 16384) ? W1 : W2;
        u16* o = (gid < 16384) ? wswz1 : wswz2;
        int j = idx & 7;
        int frag = idx >> 3;
        int l = frag & 63;
        int ks = (frag >> 6) & 3;
        int nt = frag >> 8;
        int k = ks * 32 + (l >> 4) * 8 + j;
        int n = nt * 16 + (l & 15);
        o[idx] = f2bf(W[k * HID + n]);
    }
}

// ---------------- k1: fused dinv + per-block local exclusive scan -> rploc, bsum ----
__launch_bounds__(256)
__global__ void k_scan1(const int* __restrict__ cnt, float* __restrict__ dinv,
                        int* __restrict__ rploc, int* __restrict__ bsum) {
    __shared__ int wsum[4];
    int t = threadIdx.x;
    int idx = blockIdx.x * 256 + t;           // grid 157 -> idx < 40192
    int v = (idx < N_NODES) ? cnt[idx] : 0;
    if (idx < N_NODES) dinv[idx] = rsqrtf((float)(v + 1));   // +1 self-loop
    int lane = t & 63, wv = t >> 6;
    int x = v;
    #pragma unroll
    for (int d = 1; d < 64; d <<= 1) {
        int y = __shfl_up(x, d, 64);
        if (lane >= d) x += y;
    }
    if (lane == 63) wsum[wv] = x;
    __syncthreads();
    int off = 0;
    #pragma unroll
    for (int w = 0; w < 4; ++w) { int s = wsum[w]; if (w < wv) off += s; }
    rploc[idx] = off + x - v;                 // local exclusive
    if (t == 255) bsum[blockIdx.x] = off + x; // block total
}

// ---------------- k2: CSR fill (blocks 0..2499) ∥ gemm1 z1=dinv*(x@W1) (2500..3124) ----
__launch_bounds__(256)
__global__ void k_fill_gemm1(const int* __restrict__ srcs, const int* __restrict__ dsts,
                             const int* __restrict__ rploc, const int* __restrict__ bsum,
                             int* __restrict__ cnt, int* __restrict__ csr,
                             const float* __restrict__ x, const u16* __restrict__ wswz1,
                             const float* __restrict__ dinv, u8* __restrict__ z1) {
    __shared__ u16 wlds[16384];   // 32 KB (gemm branch)
    __shared__ int sboff[NBSUM];
    __shared__ int wsum[4];
    if (blockIdx.x < 2500) {
        block_boff(bsum, sboff, wsum);
        int e = blockIdx.x * 256 + threadIdx.x;        // 640000 exact
        int s = srcs[e], d = dsts[e];
        int old = atomicSub(&cnt[d], 1);               // old in [1, deg]
        csr[rploc[d] + sboff[d >> 8] + old - 1] = s;
    } else {
        int t = threadIdx.x;
        {   // stage pre-swizzled W1: 2048 uint4 / 256 thr
            const uint4* s4 = (const uint4*)wswz1;
            uint4* d4 = (uint4*)wlds;
            #pragma unroll
            for (int i = 0; i < 8; ++i) d4[t + 256 * i] = s4[t + 256 * i];
        }
        __syncthreads();
        int lane = t & 63, wv = t >> 6;
        int quad = lane >> 4, m15 = lane & 15;
        int strip = (blockIdx.x - 2500) * 4 + wv;      // [0,2500)
        int m0 = strip * 16;
        bf16x8 af[4];
        const float* arow = x + (size_t)(m0 + m15) * HID;
        #pragma unroll
        for (int ks = 0; ks < 4; ++ks) {
            float4 u = *(const float4*)(arow + ks * 32 + quad * 8);
            float4 v = *(const float4*)(arow + ks * 32 + quad * 8 + 4);
            bf16x8 f;
            f[0] = (short)f2bf(u.x); f[1] = (short)f2bf(u.y);
            f[2] = (short)f2bf(u.z); f[3] = (short)f2bf(u.w);
            f[4] = (short)f2bf(v.x); f[5] = (short)f2bf(v.y);
            f[6] = (short)f2bf(v.z); f[7] = (short)f2bf(v.w);
            af[ks] = f;
        }
        #pragma unroll
        for (int nt = 0; nt < 8; ++nt) {
            f32x4 acc = {0.f, 0.f, 0.f, 0.f};
            #pragma unroll
            for (int ks = 0; ks < 4; ++ks) {
                bf16x8 bfr = *(const bf16x8*)(&wlds[((nt * 4 + ks) * 64 + lane) * 8]);
                acc = __builtin_amdgcn_mfma_f32_16x16x32_bf16(af[ks], bfr, acc, 0, 0, 0);
            }
            #pragma unroll
            for (int r = 0; r < 4; ++r) {
                float zc = acc[r] * dinv[m0 + quad * 4 + r];
                int pk = __builtin_amdgcn_cvt_pk_fp8_f32(zc, zc, 0, false);
                z1[(size_t)(m0 + quad * 4 + r) * HID + nt * 16 + m15] = (u8)pk;
            }
        }
    }
}

// ---------------- k3: FUSED agg1 + gemm2.  Block = 16 nodes.
// agg: h[i] = relu(dinv_i*(z1[i]+sum z1[src]) + b1) -> LDS (bf16, padded stride)
// gemm: z2 = dinv * (htile @ W2) -> fp8 into SEPARATE buffer (no aliasing with zin:
// other blocks still gather-read z1 while this block writes z2 — round-11 race fix).
__launch_bounds__(256, 8)
__global__ void k_agg_gemm(const u8* __restrict__ zin, const float* __restrict__ dinv,
                           const int* __restrict__ rploc, const int* __restrict__ bsum,
                           const int* __restrict__ csr, const float* __restrict__ bias,
                           const u16* __restrict__ wswz2, u8* __restrict__ zout) {
    __shared__ int sboff[NBSUM];
    __shared__ int wsum[4];
    __shared__ u16 htile[16 * 136];   // +8 u16 row pad -> conflict-free ds_read_b128
    block_boff(bsum, sboff, wsum);

    int t = threadIdx.x;
    int lane = t & 63, wv = t >> 6;
    int q = lane >> 4, sub = lane & 15;
    int i = blockIdx.x * 16 + wv * 4 + q;                    // 2500*16 = 40000 exact
    float di = dinv[i];
    const u8* base = zin + (size_t)sub * 8;
    uint2 ps = *(const uint2*)(base + (size_t)i * HID);
    f32x2 t0 = __builtin_amdgcn_cvt_pk_f32_fp8((int)ps.x, false);
    f32x2 t1 = __builtin_amdgcn_cvt_pk_f32_fp8((int)ps.x, true);
    f32x2 t2 = __builtin_amdgcn_cvt_pk_f32_fp8((int)ps.y, false);
    f32x2 t3 = __builtin_amdgcn_cvt_pk_f32_fp8((int)ps.y, true);
    float a0 = t0[0], a1 = t0[1], a2 = t1[0], a3 = t1[1];
    float a4 = t2[0], a5 = t2[1], a6 = t3[0], a7 = t3[1];

    int e  = rploc[i] + sboff[i >> 8];
    int e1 = rploc[i + 1] + sboff[(i + 1) >> 8];
    for (; e + 8 <= e1; e += 8) {
        int s[8];
        uint2 p[8];
        #pragma unroll
        for (int u = 0; u < 8; ++u) s[u] = csr[e + u];
        #pragma unroll
        for (int u = 0; u < 8; ++u)
            p[u] = *(const uint2*)(base + (size_t)s[u] * HID);
        #pragma unroll
        for (int u = 0; u < 8; ++u) {
            f32x2 f01 = __builtin_amdgcn_cvt_pk_f32_fp8((int)p[u].x, false);
            f32x2 f23 = __builtin_amdgcn_cvt_pk_f32_fp8((int)p[u].x, true);
            f32x2 f45 = __builtin_amdgcn_cvt_pk_f32_fp8((int)p[u].y, false);
            f32x2 f67 = __builtin_amdgcn_cvt_pk_f32_fp8((int)p[u].y, true);
            a0 += f01[0]; a1 += f01[1]; a2 += f23[0]; a3 += f23[1];
            a4 += f45[0]; a5 += f45[1]; a6 += f67[0]; a7 += f67[1];
        }
    }
    for (; e < e1; ++e) {
        uint2 p = *(const uint2*)(base + (size_t)csr[e] * HID);
        f32x2 f01 = __builtin_amdgcn_cvt_pk_f32_fp8((int)p.x, false);
        f32x2 f23 = __builtin_amdgcn_cvt_pk_f32_fp8((int)p.x, true);
        f32x2 f45 = __builtin_amdgcn_cvt_pk_f32_fp8((int)p.y, false);
        f32x2 f67 = __builtin_amdgcn_cvt_pk_f32_fp8((int)p.y, true);
        a0 += f01[0]; a1 += f01[1]; a2 += f23[0]; a3 += f23[1];
        a4 += f45[0]; a5 += f45[1]; a6 += f67[0]; a7 += f67[1];
    }
    float4 b0 = *(const float4*)(bias + sub * 8);
    float4 b1v = *(const float4*)(bias + sub * 8 + 4);
    a0 = fmaxf(di * a0 + b0.x, 0.f);  a1 = fmaxf(di * a1 + b0.y, 0.f);
    a2 = fmaxf(di * a2 + b0.z, 0.f);  a3 = fmaxf(di * a3 + b0.w, 0.f);
    a4 = fmaxf(di * a4 + b1v.x, 0.f); a5 = fmaxf(di * a5 + b1v.y, 0.f);
    a6 = fmaxf(di * a6 + b1v.z, 0.f); a7 = fmaxf(di * a7 + b1v.w, 0.f);
    int nl = wv * 4 + q;
    uint4 o;
    o.x = (uint32_t)f2bf(a0) | ((uint32_t)f2bf(a1) << 16);
    o.y = (uint32_t)f2bf(a2) | ((uint32_t)f2bf(a3) << 16);
    o.z = (uint32_t)f2bf(a4) | ((uint32_t)f2bf(a5) << 16);
    o.w = (uint32_t)f2bf(a6) | ((uint32_t)f2bf(a7) << 16);
    *(uint4*)(&htile[nl * 136 + sub * 8]) = o;
    __syncthreads();

    // gemm phase: wave wv handles ntiles wv*2, wv*2+1
    int quad = q, m15 = sub;   // same decomposition
    bf16x8 af[4];
    #pragma unroll
    for (int ks = 0; ks < 4; ++ks)
        af[ks] = *(const bf16x8*)(&htile[m15 * 136 + ks * 32 + quad * 8]);
    int m0 = blockIdx.x * 16;
    #pragma unroll
    for (int n2 = 0; n2 < 2; ++n2) {
        int nt = wv * 2 + n2;
        f32x4 acc = {0.f, 0.f, 0.f, 0.f};
        #pragma unroll
        for (int ks = 0; ks < 4; ++ks) {
            bf16x8 bfr = *(const bf16x8*)(wswz2 + ((nt * 4 + ks) * 64 + lane) * 8);
            acc = __builtin_amdgcn_mfma_f32_16x16x32_bf16(af[ks], bfr, acc, 0, 0, 0);
        }
        #pragma unroll
        for (int r = 0; r < 4; ++r) {
            float zc = acc[r] * dinv[m0 + quad * 4 + r];
            int pk = __builtin_amdgcn_cvt_pk_fp8_f32(zc, zc, 0, false);
            zout[(size_t)(m0 + quad * 4 + r) * HID + nt * 16 + m15] = (u8)pk;
        }
    }
}

// ---------------- k4: agg2  h2[i] = relu(dinv_i*(z2[i]+sum z2[src]) + b2) -> bf16 ----
__launch_bounds__(256, 8)
__global__ void k_agg2(const u8* __restrict__ zin, const float* __restrict__ dinv,
                       const int* __restrict__ rploc, const int* __restrict__ bsum,
                       const int* __restrict__ csr, const float* __restrict__ bias,
                       u16* __restrict__ out) {
    __shared__ int sboff[NBSUM];
    __shared__ int wsum[4];
    block_boff(bsum, sboff, wsum);
    int t = threadIdx.x;
    int lane = t & 63, wv = t >> 6;
    int q = lane >> 4, sub = lane & 15;
    int i = blockIdx.x * 16 + wv * 4 + q;
    float di = dinv[i];
    const u8* base = zin + (size_t)sub * 8;
    uint2 ps = *(const uint2*)(base + (size_t)i * HID);
    f32x2 t0 = __builtin_amdgcn_cvt_pk_f32_fp8((int)ps.x, false);
    f32x2 t1 = __builtin_amdgcn_cvt_pk_f32_fp8((int)ps.x, true);
    f32x2 t2 = __builtin_amdgcn_cvt_pk_f32_fp8((int)ps.y, false);
    f32x2 t3 = __builtin_amdgcn_cvt_pk_f32_fp8((int)ps.y, true);
    float a0 = t0[0], a1 = t0[1], a2 = t1[0], a3 = t1[1];
    float a4 = t2[0], a5 = t2[1], a6 = t3[0], a7 = t3[1];

    int e  = rploc[i] + sboff[i >> 8];
    int e1 = rploc[i + 1] + sboff[(i + 1) >> 8];
    for (; e + 8 <= e1; e += 8) {
        int s[8];
        uint2 p[8];
        #pragma unroll
        for (int u = 0; u < 8; ++u) s[u] = csr[e + u];
        #pragma unroll
        for (int u = 0; u < 8; ++u)
            p[u] = *(const uint2*)(base + (size_t)s[u] * HID);
        #pragma unroll
        for (int u = 0; u < 8; ++u) {
            f32x2 f01 = __builtin_amdgcn_cvt_pk_f32_fp8((int)p[u].x, false);
            f32x2 f23 = __builtin_amdgcn_cvt_pk_f32_fp8((int)p[u].x, true);
            f32x2 f45 = __builtin_amdgcn_cvt_pk_f32_fp8((int)p[u].y, false);
            f32x2 f67 = __builtin_amdgcn_cvt_pk_f32_fp8((int)p[u].y, true);
            a0 += f01[0]; a1 += f01[1]; a2 += f23[0]; a3 += f23[1];
            a4 += f45[0]; a5 += f45[1]; a6 += f67[0]; a7 += f67[1];
        }
    }
    for (; e < e1; ++e) {
        uint2 p = *(const uint2*)(base + (size_t)csr[e] * HID);
        f32x2 f01 = __builtin_amdgcn_cvt_pk_f32_fp8((int)p.x, false);
        f32x2 f23 = __builtin_amdgcn_cvt_pk_f32_fp8((int)p.x, true);
        f32x2 f45 = __builtin_amdgcn_cvt_pk_f32_fp8((int)p.y, false);
        f32x2 f67 = __builtin_amdgcn_cvt_pk_f32_fp8((int)p.y, true);
        a0 += f01[0]; a1 += f01[1]; a2 += f23[0]; a3 += f23[1];
        a4 += f45[0]; a5 += f45[1]; a6 += f67[0]; a7 += f67[1];
    }
    float4 b0 = *(const float4*)(bias + sub * 8);
    float4 b1v = *(const float4*)(bias + sub * 8 + 4);
    a0 = fmaxf(di * a0 + b0.x, 0.f);  a1 = fmaxf(di * a1 + b0.y, 0.f);
    a2 = fmaxf(di * a2 + b0.z, 0.f);  a3 = fmaxf(di * a3 + b0.w, 0.f);
    a4 = fmaxf(di * a4 + b1v.x, 0.f); a5 = fmaxf(di * a5 + b1v.y, 0.f);
    a6 = fmaxf(di * a6 + b1v.z, 0.f); a7 = fmaxf(di * a7 + b1v.w, 0.f);
    uint4 o;
    o.x = (uint32_t)f2bf(a0) | ((uint32_t)f2bf(a1) << 16);
    o.y = (uint32_t)f2bf(a2) | ((uint32_t)f2bf(a3) << 16);
    o.z = (uint32_t)f2bf(a4) | ((uint32_t)f2bf(a5) << 16);
    o.w = (uint32_t)f2bf(a6) | ((uint32_t)f2bf(a7) << 16);
    *(uint4*)(out + (size_t)i * HID + sub * 8) = o;
}

// ---------------- pool stage 1: 64 graphs x 16 splits; uint2 loads, LDS reduce ----
__launch_bounds__(256)
__global__ void k_pool1(const u16* __restrict__ h, const int* __restrict__ batch,
                        float* __restrict__ partial) {
    __shared__ float red[8][HID];
    int g = blockIdx.x >> 4;           // / NSPLIT
    int s = blockIdx.x & (NSPLIT - 1);
    int t = threadIdx.x;               // c = uint2 chunk (4 feats), tr = row lane (8 rows)
    int c = t & 31, tr = t >> 5;
    int lo = 0, n = N_NODES;
    while (n > 0) { int half = n >> 1; int mid = lo + half;
        if (batch[mid] < g) { lo = mid + 1; n -= half + 1; } else n = half; }
    int hi = lo, n2 = N_NODES - lo;
    while (n2 > 0) { int half = n2 >> 1; int mid = hi + half;
        if (batch[mid] < g + 1) { hi = mid + 1; n2 -= half + 1; } else n2 = half; }
    int len = (hi - lo + NSPLIT - 1) / NSPLIT;
    int r0 = lo + s * len;
    int r1 = min(r0 + len, hi);
    float a0 = 0.f, a1 = 0.f, a2 = 0.f, a3 = 0.f;
    for (int r = r0 + tr; r < r1; r += 8) {
        uint2 v = *(const uint2*)(h + (size_t)r * HID + c * 4);
        a0 += bf2f((u16)(v.x & 0xffff)); a1 += bf2f((u16)(v.x >> 16));
        a2 += bf2f((u16)(v.y & 0xffff)); a3 += bf2f((u16)(v.y >> 16));
    }
    red[tr][c * 4 + 0] = a0; red[tr][c * 4 + 1] = a1;
    red[tr][c * 4 + 2] = a2; red[tr][c * 4 + 3] = a3;
    __syncthreads();
    if (t < HID) {
        float acc = 0.f;
        #pragma unroll
        for (int j = 0; j < 8; ++j) acc += red[j][t];
        partial[(size_t)blockIdx.x * HID + t] = acc;
    }
}

// ---------------- pool stage 2: reduce 16 partials, mean, fused linear ----------------
__launch_bounds__(128)
__global__ void k_pool2(const float* __restrict__ partial, const int* __restrict__ batch,
                        const float* __restrict__ lin_w, const float* __restrict__ lin_b,
                        float* __restrict__ outp) {
    __shared__ float sh[HID];
    int g = blockIdx.x;
    int t = threadIdx.x;   // 128 threads, thread = feature
    int lo = 0, n = N_NODES;
    while (n > 0) { int half = n >> 1; int mid = lo + half;
        if (batch[mid] < g) { lo = mid + 1; n -= half + 1; } else n = half; }
    int hi = lo, n2 = N_NODES - lo;
    while (n2 > 0) { int half = n2 >> 1; int mid = hi + half;
        if (batch[mid] < g + 1) { hi = mid + 1; n2 -= half + 1; } else n2 = half; }
    float acc = 0.f;
    #pragma unroll
    for (int s = 0; s < NSPLIT; ++s)
        acc += partial[(size_t)(g * NSPLIT + s) * HID + t];
    float c = fmaxf((float)(hi - lo), 1.f);
    sh[t] = acc / c;
    __syncthreads();
    if (t < NCLASS) {
        float a = lin_b[t];
        #pragma unroll 8
        for (int f = 0; f < HID; ++f)
            a += sh[f] * lin_w[f * NCLASS + t];
        outp[g * NCLASS + t] = a;
    }
}

extern "C" void kernel_launch(void* const* d_in, const int* in_sizes, int n_in,
                              void* d_out, int out_size, void* d_ws, size_t ws_size,
                              hipStream_t stream) {
    const float* x    = (const float*)d_in[0];
    const int* eidx   = (const int*)d_in[1];
    const int* batch  = (const int*)d_in[2];
    const float* W1   = (const float*)d_in[3];
    const float* b1   = (const float*)d_in[4];
    const float* W2   = (const float*)d_in[5];
    const float* b2   = (const float*)d_in[6];
    const float* lw   = (const float*)d_in[7];
    const float* lb   = (const float*)d_in[8];
    float* out = (float*)d_out;

    char* ws = (char*)d_ws;
    int*   cnt     = (int*)(ws + 0);                 // 160000 B (memset region)
    int*   bsum    = (int*)(ws + 160000);            // 628 B -> pad 161024
    int*   rploc   = (int*)(ws + 161024);            // 160768 B (40192 ints)
    float* dinv    = (float*)(ws + 321792);          // 160000 B
    int*   csr     = (int*)(ws + 481792);            // 2560000 B
    u16*   wswz1   = (u16*)(ws + 3041792);           // 32768 B
    u16*   wswz2   = (u16*)(ws + 3074560);           // 32768 B
    float* partial = (float*)(ws + 3107328);         // 524288 B
    u8*    bufZ1   = (u8*)(ws + 3631616);            // 5120000 B (fp8 z1 rows)
    u8*    bufZ2   = (u8*)(ws + 8751616);            // 5120000 B (fp8 z2 rows — separate!)
    u16*   bufH    = (u16*)(ws + 13871616);          // 10240000 B (bf16 h2 rows) ~24.1 MB

    const int* src = eidx;             // edge_index[0]
    const int* dst = eidx + N_EDGES;   // edge_index[1]

    hipMemsetAsync(d_ws, 0, 160000, stream);
    k_deg_wprep<<<2628, 256, 0, stream>>>(dst, cnt, W1, W2, wswz1, wswz2);
    k_scan1<<<157, 256, 0, stream>>>(cnt, dinv, rploc, bsum);
    k_fill_gemm1<<<3125, 256, 0, stream>>>(src, dst, rploc, bsum, cnt, csr,
                                           x, wswz1, dinv, bufZ1);       // csr + z1
    k_agg_gemm<<<2500, 256, 0, stream>>>(bufZ1, dinv, rploc, bsum, csr, b1,
                                         wswz2, bufZ2);                  // h1 in LDS -> z2
    k_agg2<<<2500, 256, 0, stream>>>(bufZ2, dinv, rploc, bsum, csr, b2, bufH); // h2
    k_pool1<<<NGRAPH * NSPLIT, 256, 0, stream>>>(bufH, batch, partial);
    k_pool2<<<NGRAPH, 128, 0, stream>>>(partial, batch, lw, lb, out);
}

// Round 13
// 202.222 us; speedup vs baseline: 3.6262x; 1.0407x over previous
//
#include <hip/hip_runtime.h>
#include <stdint.h>

#define N_NODES 40000
#define N_EDGES 640000
#define HID 128
#define NGRAPH 64
#define NCLASS 10
#define NBSUM 157           // ceil(40000/256)

typedef unsigned short u16;
typedef unsigned char u8;
typedef __attribute__((ext_vector_type(8))) short bf16x8;
typedef __attribute__((ext_vector_type(4))) float f32x4;
typedef __attribute__((ext_vector_type(2))) float f32x2;

static __device__ __forceinline__ float bf2f(u16 u) {
    union { uint32_t i; float f; } v; v.i = ((uint32_t)u) << 16; return v.f;
}
static __device__ __forceinline__ u16 f2bf(float f) {
    union { float f; uint32_t i; } v; v.f = f;
    uint32_t u = v.i;
    u = (u + 0x7fff + ((u >> 16) & 1)) >> 16;   // RNE
    return (u16)u;
}

// per-block recompute of boff (exclusive scan of 157 block sums) into LDS.
static __device__ __forceinline__ void block_boff(const int* __restrict__ bsum,
                                                  int* sboff, int* wsum) {
    int t = threadIdx.x;
    int v = (t < NBSUM) ? bsum[t] : 0;
    int lane = t & 63, wv = t >> 6;
    int x = v;
    #pragma unroll
    for (int d = 1; d < 64; d <<= 1) {
        int y = __shfl_up(x, d, 64);
        if (lane >= d) x += y;
    }
    if (lane == 63) wsum[wv] = x;
    __syncthreads();
    int off = 0;
    #pragma unroll
    for (int w = 0; w < 4; ++w) { int s = wsum[w]; if (w < wv) off += s; }
    if (t < NBSUM) sboff[t] = off + x - v;
    __syncthreads();
}

// ---------------- k0: degree histogram (blocks 0..2499) ∥ W pre-swizzle (2500..2627) ----
__launch_bounds__(256)
__global__ void k_deg_wprep(const int* __restrict__ dst, int* __restrict__ cnt,
                            const float* __restrict__ W1, const float* __restrict__ W2,
                            u16* __restrict__ wswz1, u16* __restrict__ wswz2) {
    if (blockIdx.x < 2500) {
        int e = blockIdx.x * 256 + threadIdx.x;        // 640000 exact
        atomicAdd(&cnt[dst[e]], 1);
    } else {
        int gid = (blockIdx.x - 2500) * 256 + threadIdx.x;   // [0,32768)
        int idx = gid & 16383;
        const float* W = (gid < 16384) ? W1 : W2;
        u16* o = (gid < 16384) ? wswz1 : wswz2;
        int j = idx & 7;
        int frag = idx >> 3;
        int l = frag & 63;
        int ks = (frag >> 6) & 3;
        int nt = frag >> 8;
        int k = ks * 32 + (l >> 4) * 8 + j;
        int n = nt * 16 + (l & 15);
        o[idx] = f2bf(W[k * HID + n]);
    }
}

// ---------------- k1: fused dinv + per-block local exclusive scan -> rploc, bsum ----
__launch_bounds__(256)
__global__ void k_scan1(const int* __restrict__ cnt, float* __restrict__ dinv,
                        int* __restrict__ rploc, int* __restrict__ bsum) {
    __shared__ int wsum[4];
    int t = threadIdx.x;
    int idx = blockIdx.x * 256 + t;           // grid 157 -> idx < 40192
    int v = (idx < N_NODES) ? cnt[idx] : 0;
    if (idx < N_NODES) dinv[idx] = rsqrtf((float)(v + 1));   // +1 self-loop
    int lane = t & 63, wv = t >> 6;
    int x = v;
    #pragma unroll
    for (int d = 1; d < 64; d <<= 1) {
        int y = __shfl_up(x, d, 64);
        if (lane >= d) x += y;
    }
    if (lane == 63) wsum[wv] = x;
    __syncthreads();
    int off = 0;
    #pragma unroll
    for (int w = 0; w < 4; ++w) { int s = wsum[w]; if (w < wv) off += s; }
    rploc[idx] = off + x - v;                 // local exclusive
    if (t == 255) bsum[blockIdx.x] = off + x; // block total
}

// ---------------- k2: CSR fill (blocks 0..2499) ∥ gemm1 z1=dinv*(x@W1) (2500..3124) ----
__launch_bounds__(256)
__global__ void k_fill_gemm1(const int* __restrict__ srcs, const int* __restrict__ dsts,
                             const int* __restrict__ rploc, const int* __restrict__ bsum,
                             int* __restrict__ cnt, int* __restrict__ csr,
                             const float* __restrict__ x, const u16* __restrict__ wswz1,
                             const float* __restrict__ dinv, u8* __restrict__ z1) {
    __shared__ u16 wlds[16384];   // 32 KB (gemm branch)
    __shared__ int sboff[NBSUM];
    __shared__ int wsum[4];
    if (blockIdx.x < 2500) {
        block_boff(bsum, sboff, wsum);
        int e = blockIdx.x * 256 + threadIdx.x;        // 640000 exact
        int s = srcs[e], d = dsts[e];
        int old = atomicSub(&cnt[d], 1);               // old in [1, deg]
        csr[rploc[d] + sboff[d >> 8] + old - 1] = s;
    } else {
        int t = threadIdx.x;
        {   // stage pre-swizzled W1: 2048 uint4 / 256 thr
            const uint4* s4 = (const uint4*)wswz1;
            uint4* d4 = (uint4*)wlds;
            #pragma unroll
            for (int i = 0; i < 8; ++i) d4[t + 256 * i] = s4[t + 256 * i];
        }
        __syncthreads();
        int lane = t & 63, wv = t >> 6;
        int quad = lane >> 4, m15 = lane & 15;
        int strip = (blockIdx.x - 2500) * 4 + wv;      // [0,2500)
        int m0 = strip * 16;
        bf16x8 af[4];
        const float* arow = x + (size_t)(m0 + m15) * HID;
        #pragma unroll
        for (int ks = 0; ks < 4; ++ks) {
            float4 u = *(const float4*)(arow + ks * 32 + quad * 8);
            float4 v = *(const float4*)(arow + ks * 32 + quad * 8 + 4);
            bf16x8 f;
            f[0] = (short)f2bf(u.x); f[1] = (short)f2bf(u.y);
            f[2] = (short)f2bf(u.z); f[3] = (short)f2bf(u.w);
            f[4] = (short)f2bf(v.x); f[5] = (short)f2bf(v.y);
            f[6] = (short)f2bf(v.z); f[7] = (short)f2bf(v.w);
            af[ks] = f;
        }
        #pragma unroll
        for (int nt = 0; nt < 8; ++nt) {
            f32x4 acc = {0.f, 0.f, 0.f, 0.f};
            #pragma unroll
            for (int ks = 0; ks < 4; ++ks) {
                bf16x8 bfr = *(const bf16x8*)(&wlds[((nt * 4 + ks) * 64 + lane) * 8]);
                acc = __builtin_amdgcn_mfma_f32_16x16x32_bf16(af[ks], bfr, acc, 0, 0, 0);
            }
            #pragma unroll
            for (int r = 0; r < 4; ++r) {
                float zc = acc[r] * dinv[m0 + quad * 4 + r];
                int pk = __builtin_amdgcn_cvt_pk_fp8_f32(zc, zc, 0, false);
                z1[(size_t)(m0 + quad * 4 + r) * HID + nt * 16 + m15] = (u8)pk;
            }
        }
    }
}

// ---------------- k3: FUSED agg1 + gemm2.  Block = 16 nodes.  z1 -> h1(LDS) -> z2 ----
__launch_bounds__(256, 8)
__global__ void k_agg_gemm(const u8* __restrict__ zin, const float* __restrict__ dinv,
                           const int* __restrict__ rploc, const int* __restrict__ bsum,
                           const int* __restrict__ csr, const float* __restrict__ bias,
                           const u16* __restrict__ wswz2, u8* __restrict__ zout) {
    __shared__ int sboff[NBSUM];
    __shared__ int wsum[4];
    __shared__ u16 htile[16 * 136];   // +8 u16 row pad -> conflict-free ds_read_b128
    block_boff(bsum, sboff, wsum);

    int t = threadIdx.x;
    int lane = t & 63, wv = t >> 6;
    int q = lane >> 4, sub = lane & 15;
    int i = blockIdx.x * 16 + wv * 4 + q;                    // 2500*16 = 40000 exact
    float di = dinv[i];
    const u8* base = zin + (size_t)sub * 8;
    uint2 ps = *(const uint2*)(base + (size_t)i * HID);
    f32x2 t0 = __builtin_amdgcn_cvt_pk_f32_fp8((int)ps.x, false);
    f32x2 t1 = __builtin_amdgcn_cvt_pk_f32_fp8((int)ps.x, true);
    f32x2 t2 = __builtin_amdgcn_cvt_pk_f32_fp8((int)ps.y, false);
    f32x2 t3 = __builtin_amdgcn_cvt_pk_f32_fp8((int)ps.y, true);
    float a0 = t0[0], a1 = t0[1], a2 = t1[0], a3 = t1[1];
    float a4 = t2[0], a5 = t2[1], a6 = t3[0], a7 = t3[1];

    int e  = rploc[i] + sboff[i >> 8];
    int e1 = rploc[i + 1] + sboff[(i + 1) >> 8];
    for (; e + 8 <= e1; e += 8) {
        int s[8];
        uint2 p[8];
        #pragma unroll
        for (int u = 0; u < 8; ++u) s[u] = csr[e + u];
        #pragma unroll
        for (int u = 0; u < 8; ++u)
            p[u] = *(const uint2*)(base + (size_t)s[u] * HID);
        #pragma unroll
        for (int u = 0; u < 8; ++u) {
            f32x2 f01 = __builtin_amdgcn_cvt_pk_f32_fp8((int)p[u].x, false);
            f32x2 f23 = __builtin_amdgcn_cvt_pk_f32_fp8((int)p[u].x, true);
            f32x2 f45 = __builtin_amdgcn_cvt_pk_f32_fp8((int)p[u].y, false);
            f32x2 f67 = __builtin_amdgcn_cvt_pk_f32_fp8((int)p[u].y, true);
            a0 += f01[0]; a1 += f01[1]; a2 += f23[0]; a3 += f23[1];
            a4 += f45[0]; a5 += f45[1]; a6 += f67[0]; a7 += f67[1];
        }
    }
    for (; e < e1; ++e) {
        uint2 p = *(const uint2*)(base + (size_t)csr[e] * HID);
        f32x2 f01 = __builtin_amdgcn_cvt_pk_f32_fp8((int)p.x, false);
        f32x2 f23 = __builtin_amdgcn_cvt_pk_f32_fp8((int)p.x, true);
        f32x2 f45 = __builtin_amdgcn_cvt_pk_f32_fp8((int)p.y, false);
        f32x2 f67 = __builtin_amdgcn_cvt_pk_f32_fp8((int)p.y, true);
        a0 += f01[0]; a1 += f01[1]; a2 += f23[0]; a3 += f23[1];
        a4 += f45[0]; a5 += f45[1]; a6 += f67[0]; a7 += f67[1];
    }
    float4 b0 = *(const float4*)(bias + sub * 8);
    float4 b1v = *(const float4*)(bias + sub * 8 + 4);
    a0 = fmaxf(di * a0 + b0.x, 0.f);  a1 = fmaxf(di * a1 + b0.y, 0.f);
    a2 = fmaxf(di * a2 + b0.z, 0.f);  a3 = fmaxf(di * a3 + b0.w, 0.f);
    a4 = fmaxf(di * a4 + b1v.x, 0.f); a5 = fmaxf(di * a5 + b1v.y, 0.f);
    a6 = fmaxf(di * a6 + b1v.z, 0.f); a7 = fmaxf(di * a7 + b1v.w, 0.f);
    int nl = wv * 4 + q;
    uint4 o;
    o.x = (uint32_t)f2bf(a0) | ((uint32_t)f2bf(a1) << 16);
    o.y = (uint32_t)f2bf(a2) | ((uint32_t)f2bf(a3) << 16);
    o.z = (uint32_t)f2bf(a4) | ((uint32_t)f2bf(a5) << 16);
    o.w = (uint32_t)f2bf(a6) | ((uint32_t)f2bf(a7) << 16);
    *(uint4*)(&htile[nl * 136 + sub * 8]) = o;
    __syncthreads();

    // gemm phase: wave wv handles ntiles wv*2, wv*2+1
    int quad = q, m15 = sub;   // same decomposition
    bf16x8 af[4];
    #pragma unroll
    for (int ks = 0; ks < 4; ++ks)
        af[ks] = *(const bf16x8*)(&htile[m15 * 136 + ks * 32 + quad * 8]);
    int m0 = blockIdx.x * 16;
    #pragma unroll
    for (int n2 = 0; n2 < 2; ++n2) {
        int nt = wv * 2 + n2;
        f32x4 acc = {0.f, 0.f, 0.f, 0.f};
        #pragma unroll
        for (int ks = 0; ks < 4; ++ks) {
            bf16x8 bfr = *(const bf16x8*)(wswz2 + ((nt * 4 + ks) * 64 + lane) * 8);
            acc = __builtin_amdgcn_mfma_f32_16x16x32_bf16(af[ks], bfr, acc, 0, 0, 0);
        }
        #pragma unroll
        for (int r = 0; r < 4; ++r) {
            float zc = acc[r] * dinv[m0 + quad * 4 + r];
            int pk = __builtin_amdgcn_cvt_pk_fp8_f32(zc, zc, 0, false);
            zout[(size_t)(m0 + quad * 4 + r) * HID + nt * 16 + m15] = (u8)pk;
        }
    }
}

// ---------------- k4: FUSED agg2 + pooling.  h2 never hits HBM.
// h2 rows -> fp32 LDS tile; segmented per-block reduce over sorted batch;
// ~128*~1.03 atomicAdds/block into pool[64][128] (≈40 hits/address total).
__launch_bounds__(256, 8)
__global__ void k_agg2pool(const u8* __restrict__ zin, const float* __restrict__ dinv,
                           const int* __restrict__ rploc, const int* __restrict__ bsum,
                           const int* __restrict__ csr, const float* __restrict__ bias,
                           const int* __restrict__ batch, float* __restrict__ pool) {
    __shared__ int sboff[NBSUM];
    __shared__ int wsum[4];
    __shared__ float hf[16 * 132];   // fp32 rows, +4 pad
    __shared__ int sbatch[16];
    block_boff(bsum, sboff, wsum);
    int t = threadIdx.x;
    int lane = t & 63, wv = t >> 6;
    int q = lane >> 4, sub = lane & 15;
    int i = blockIdx.x * 16 + wv * 4 + q;
    if (t < 16) sbatch[t] = batch[blockIdx.x * 16 + t];
    float di = dinv[i];
    const u8* base = zin + (size_t)sub * 8;
    uint2 ps = *(const uint2*)(base + (size_t)i * HID);
    f32x2 t0 = __builtin_amdgcn_cvt_pk_f32_fp8((int)ps.x, false);
    f32x2 t1 = __builtin_amdgcn_cvt_pk_f32_fp8((int)ps.x, true);
    f32x2 t2 = __builtin_amdgcn_cvt_pk_f32_fp8((int)ps.y, false);
    f32x2 t3 = __builtin_amdgcn_cvt_pk_f32_fp8((int)ps.y, true);
    float a0 = t0[0], a1 = t0[1], a2 = t1[0], a3 = t1[1];
    float a4 = t2[0], a5 = t2[1], a6 = t3[0], a7 = t3[1];

    int e  = rploc[i] + sboff[i >> 8];
    int e1 = rploc[i + 1] + sboff[(i + 1) >> 8];
    for (; e + 8 <= e1; e += 8) {
        int s[8];
        uint2 p[8];
        #pragma unroll
        for (int u = 0; u < 8; ++u) s[u] = csr[e + u];
        #pragma unroll
        for (int u = 0; u < 8; ++u)
            p[u] = *(const uint2*)(base + (size_t)s[u] * HID);
        #pragma unroll
        for (int u = 0; u < 8; ++u) {
            f32x2 f01 = __builtin_amdgcn_cvt_pk_f32_fp8((int)p[u].x, false);
            f32x2 f23 = __builtin_amdgcn_cvt_pk_f32_fp8((int)p[u].x, true);
            f32x2 f45 = __builtin_amdgcn_cvt_pk_f32_fp8((int)p[u].y, false);
            f32x2 f67 = __builtin_amdgcn_cvt_pk_f32_fp8((int)p[u].y, true);
            a0 += f01[0]; a1 += f01[1]; a2 += f23[0]; a3 += f23[1];
            a4 += f45[0]; a5 += f45[1]; a6 += f67[0]; a7 += f67[1];
        }
    }
    for (; e < e1; ++e) {
        uint2 p = *(const uint2*)(base + (size_t)csr[e] * HID);
        f32x2 f01 = __builtin_amdgcn_cvt_pk_f32_fp8((int)p.x, false);
        f32x2 f23 = __builtin_amdgcn_cvt_pk_f32_fp8((int)p.x, true);
        f32x2 f45 = __builtin_amdgcn_cvt_pk_f32_fp8((int)p.y, false);
        f32x2 f67 = __builtin_amdgcn_cvt_pk_f32_fp8((int)p.y, true);
        a0 += f01[0]; a1 += f01[1]; a2 += f23[0]; a3 += f23[1];
        a4 += f45[0]; a5 += f45[1]; a6 += f67[0]; a7 += f67[1];
    }
    float4 b0 = *(const float4*)(bias + sub * 8);
    float4 b1v = *(const float4*)(bias + sub * 8 + 4);
    int nl = wv * 4 + q;
    float* hrow = &hf[nl * 132 + sub * 8];
    float4 o0, o1;
    o0.x = fmaxf(di * a0 + b0.x, 0.f);  o0.y = fmaxf(di * a1 + b0.y, 0.f);
    o0.z = fmaxf(di * a2 + b0.z, 0.f);  o0.w = fmaxf(di * a3 + b0.w, 0.f);
    o1.x = fmaxf(di * a4 + b1v.x, 0.f); o1.y = fmaxf(di * a5 + b1v.y, 0.f);
    o1.z = fmaxf(di * a6 + b1v.z, 0.f); o1.w = fmaxf(di * a7 + b1v.w, 0.f);
    *(float4*)hrow = o0;
    *(float4*)(hrow + 4) = o1;
    __syncthreads();

    if (t < HID) {
        float s = 0.f;
        int gcur = sbatch[0];
        #pragma unroll
        for (int j = 0; j < 16; ++j) {
            int gj = sbatch[j];
            if (gj != gcur) {                       // segment boundary (rare)
                atomicAdd(&pool[gcur * HID + t], s);
                s = 0.f;
                gcur = gj;
            }
            s += hf[j * 132 + t];
        }
        atomicAdd(&pool[gcur * HID + t], s);
    }
}

// ---------------- k5: pool -> mean -> linear ----------------
__launch_bounds__(128)
__global__ void k_pool2(const float* __restrict__ pool, const int* __restrict__ batch,
                        const float* __restrict__ lin_w, const float* __restrict__ lin_b,
                        float* __restrict__ outp) {
    __shared__ float sh[HID];
    int g = blockIdx.x;
    int t = threadIdx.x;   // 128 threads, thread = feature
    int lo = 0, n = N_NODES;
    while (n > 0) { int half = n >> 1; int mid = lo + half;
        if (batch[mid] < g) { lo = mid + 1; n -= half + 1; } else n = half; }
    int hi = lo, n2 = N_NODES - lo;
    while (n2 > 0) { int half = n2 >> 1; int mid = hi + half;
        if (batch[mid] < g + 1) { hi = mid + 1; n2 -= half + 1; } else n2 = half; }
    float c = fmaxf((float)(hi - lo), 1.f);
    sh[t] = pool[g * HID + t] / c;
    __syncthreads();
    if (t < NCLASS) {
        float a = lin_b[t];
        #pragma unroll 8
        for (int f = 0; f < HID; ++f)
            a += sh[f] * lin_w[f * NCLASS + t];
        outp[g * NCLASS + t] = a;
    }
}

extern "C" void kernel_launch(void* const* d_in, const int* in_sizes, int n_in,
                              void* d_out, int out_size, void* d_ws, size_t ws_size,
                              hipStream_t stream) {
    const float* x    = (const float*)d_in[0];
    const int* eidx   = (const int*)d_in[1];
    const int* batch  = (const int*)d_in[2];
    const float* W1   = (const float*)d_in[3];
    const float* b1   = (const float*)d_in[4];
    const float* W2   = (const float*)d_in[5];
    const float* b2   = (const float*)d_in[6];
    const float* lw   = (const float*)d_in[7];
    const float* lb   = (const float*)d_in[8];
    float* out = (float*)d_out;

    char* ws = (char*)d_ws;
    int*   cnt     = (int*)(ws + 0);                 // 160000 B \ memset
    float* pool    = (float*)(ws + 160000);          // 32768 B  / [0,192768)
    int*   bsum    = (int*)(ws + 192768);            // 1024 B
    int*   rploc   = (int*)(ws + 193792);            // 160768 B (40192 ints)
    float* dinv    = (float*)(ws + 354560);          // 160000 B
    int*   csr     = (int*)(ws + 514560);            // 2560000 B
    u16*   wswz1   = (u16*)(ws + 3074560);           // 32768 B
    u16*   wswz2   = (u16*)(ws + 3107328);           // 32768 B
    u8*    bufZ1   = (u8*)(ws + 3140096);            // 5120000 B (fp8 z1)
    u8*    bufZ2   = (u8*)(ws + 8260096);            // 5120000 B (fp8 z2)  ~13.4 MB total

    const int* src = eidx;             // edge_index[0]
    const int* dst = eidx + N_EDGES;   // edge_index[1]

    hipMemsetAsync(d_ws, 0, 192768, stream);
    k_deg_wprep<<<2628, 256, 0, stream>>>(dst, cnt, W1, W2, wswz1, wswz2);
    k_scan1<<<157, 256, 0, stream>>>(cnt, dinv, rploc, bsum);
    k_fill_gemm1<<<3125, 256, 0, stream>>>(src, dst, rploc, bsum, cnt, csr,
                                           x, wswz1, dinv, bufZ1);       // csr + z1
    k_agg_gemm<<<2500, 256, 0, stream>>>(bufZ1, dinv, rploc, bsum, csr, b1,
                                         wswz2, bufZ2);                  // h1 in LDS -> z2
    k_agg2pool<<<2500, 256, 0, stream>>>(bufZ2, dinv, rploc, bsum, csr, b2,
                                         batch, pool);                   // h2 -> pool sums
    k_pool2<<<NGRAPH, 128, 0, stream>>>(pool, batch, lw, lb, out);
}

// Round 14
// 199.281 us; speedup vs baseline: 3.6797x; 1.0148x over previous
//
#include <hip/hip_runtime.h>
#include <stdint.h>

#define N_NODES 40000
#define N_EDGES 640000
#define HID 128
#define NGRAPH 64
#define NCLASS 10
#define NBSUM 157           // ceil(40000/256)

typedef unsigned short u16;
typedef unsigned char u8;
typedef __attribute__((ext_vector_type(8))) short bf16x8;
typedef __attribute__((ext_vector_type(4))) float f32x4;
typedef __attribute__((ext_vector_type(2))) float f32x2;

static __device__ __forceinline__ float bf2f(u16 u) {
    union { uint32_t i; float f; } v; v.i = ((uint32_t)u) << 16; return v.f;
}
static __device__ __forceinline__ u16 f2bf(float f) {
    union { float f; uint32_t i; } v; v.f = f;
    uint32_t u = v.i;
    u = (u + 0x7fff + ((u >> 16) & 1)) >> 16;   // RNE
    return (u16)u;
}

// per-block recompute of boff (exclusive scan of 157 block sums) into LDS.
static __device__ __forceinline__ void block_boff(const int* __restrict__ bsum,
                                                  int* sboff, int* wsum) {
    int t = threadIdx.x;
    int v = (t < NBSUM) ? bsum[t] : 0;
    int lane = t & 63, wv = t >> 6;
    int x = v;
    #pragma unroll
    for (int d = 1; d < 64; d <<= 1) {
        int y = __shfl_up(x, d, 64);
        if (lane >= d) x += y;
    }
    if (lane == 63) wsum[wv] = x;
    __syncthreads();
    int off = 0;
    #pragma unroll
    for (int w = 0; w < 4; ++w) { int s = wsum[w]; if (w < wv) off += s; }
    if (t < NBSUM) sboff[t] = off + x - v;
    __syncthreads();
}

static __device__ __forceinline__ void acc_row(uint2 p, float* a) {
    f32x2 f01 = __builtin_amdgcn_cvt_pk_f32_fp8((int)p.x, false);
    f32x2 f23 = __builtin_amdgcn_cvt_pk_f32_fp8((int)p.x, true);
    f32x2 f45 = __builtin_amdgcn_cvt_pk_f32_fp8((int)p.y, false);
    f32x2 f67 = __builtin_amdgcn_cvt_pk_f32_fp8((int)p.y, true);
    a[0] += f01[0]; a[1] += f01[1]; a[2] += f23[0]; a[3] += f23[1];
    a[4] += f45[0]; a[5] += f45[1]; a[6] += f67[0]; a[7] += f67[1];
}

// Software-pipelined gather: while converting batch k, batch k+1 (csr + rows)
// is in flight. Unroll 6 keeps VGPR under the 64-reg / 8-wave budget.
// Consumption order per lane == edge order -> bit-identical to unrolled-8 loop.
static __device__ __forceinline__ void agg_gather(const u8* __restrict__ base,
        const int* __restrict__ csr, int e, int e1, float* a) {
    if (e + 6 <= e1) {
        int sc[6]; uint2 pc[6];
        #pragma unroll
        for (int u = 0; u < 6; ++u) sc[u] = csr[e + u];
        #pragma unroll
        for (int u = 0; u < 6; ++u) pc[u] = *(const uint2*)(base + (size_t)sc[u] * HID);
        e += 6;
        while (e + 6 <= e1) {
            int sn[6]; uint2 pn[6];
            #pragma unroll
            for (int u = 0; u < 6; ++u) sn[u] = csr[e + u];
            #pragma unroll
            for (int u = 0; u < 6; ++u) pn[u] = *(const uint2*)(base + (size_t)sn[u] * HID);
            #pragma unroll
            for (int u = 0; u < 6; ++u) acc_row(pc[u], a);
            #pragma unroll
            for (int u = 0; u < 6; ++u) { sc[u] = sn[u]; pc[u] = pn[u]; }
            e += 6;
        }
        #pragma unroll
        for (int u = 0; u < 6; ++u) acc_row(pc[u], a);
    }
    for (; e < e1; ++e) {
        uint2 p = *(const uint2*)(base + (size_t)csr[e] * HID);
        acc_row(p, a);
    }
}

// ---------------- k0: degree histogram (blocks 0..2499) ∥ W pre-swizzle (2500..2627) ----
__launch_bounds__(256)
__global__ void k_deg_wprep(const int* __restrict__ dst, int* __restrict__ cnt,
                            const float* __restrict__ W1, const float* __restrict__ W2,
                            u16* __restrict__ wswz1, u16* __restrict__ wswz2) {
    if (blockIdx.x < 2500) {
        int e = blockIdx.x * 256 + threadIdx.x;        // 640000 exact
        atomicAdd(&cnt[dst[e]], 1);
    } else {
        int gid = (blockIdx.x - 2500) * 256 + threadIdx.x;   // [0,32768)
        int idx = gid & 16383;
        const float* W = (gid < 16384) ? W1 : W2;
        u16* o = (gid < 16384) ? wswz1 : wswz2;
        int j = idx & 7;
        int frag = idx >> 3;
        int l = frag & 63;
        int ks = (frag >> 6) & 3;
        int nt = frag >> 8;
        int k = ks * 32 + (l >> 4) * 8 + j;
        int n = nt * 16 + (l & 15);
        o[idx] = f2bf(W[k * HID + n]);
    }
}

// ---------------- k1: fused dinv + per-block local exclusive scan -> rploc, bsum ----
__launch_bounds__(256)
__global__ void k_scan1(const int* __restrict__ cnt, float* __restrict__ dinv,
                        int* __restrict__ rploc, int* __restrict__ bsum) {
    __shared__ int wsum[4];
    int t = threadIdx.x;
    int idx = blockIdx.x * 256 + t;           // grid 157 -> idx < 40192
    int v = (idx < N_NODES) ? cnt[idx] : 0;
    if (idx < N_NODES) dinv[idx] = rsqrtf((float)(v + 1));   // +1 self-loop
    int lane = t & 63, wv = t >> 6;
    int x = v;
    #pragma unroll
    for (int d = 1; d < 64; d <<= 1) {
        int y = __shfl_up(x, d, 64);
        if (lane >= d) x += y;
    }
    if (lane == 63) wsum[wv] = x;
    __syncthreads();
    int off = 0;
    #pragma unroll
    for (int w = 0; w < 4; ++w) { int s = wsum[w]; if (w < wv) off += s; }
    rploc[idx] = off + x - v;                 // local exclusive
    if (t == 255) bsum[blockIdx.x] = off + x; // block total
}

// ---------------- k2: CSR fill (blocks 0..2499) ∥ gemm1 z1=dinv*(x@W1) (2500..3124) ----
__launch_bounds__(256)
__global__ void k_fill_gemm1(const int* __restrict__ srcs, const int* __restrict__ dsts,
                             const int* __restrict__ rploc, const int* __restrict__ bsum,
                             int* __restrict__ cnt, int* __restrict__ csr,
                             const float* __restrict__ x, const u16* __restrict__ wswz1,
                             const float* __restrict__ dinv, u8* __restrict__ z1) {
    __shared__ u16 wlds[16384];   // 32 KB (gemm branch)
    __shared__ int sboff[NBSUM];
    __shared__ int wsum[4];
    if (blockIdx.x < 2500) {
        block_boff(bsum, sboff, wsum);
        int e = blockIdx.x * 256 + threadIdx.x;        // 640000 exact
        int s = srcs[e], d = dsts[e];
        int old = atomicSub(&cnt[d], 1);               // old in [1, deg]
        csr[rploc[d] + sboff[d >> 8] + old - 1] = s;
    } else {
        int t = threadIdx.x;
        {   // stage pre-swizzled W1: 2048 uint4 / 256 thr
            const uint4* s4 = (const uint4*)wswz1;
            uint4* d4 = (uint4*)wlds;
            #pragma unroll
            for (int i = 0; i < 8; ++i) d4[t + 256 * i] = s4[t + 256 * i];
        }
        __syncthreads();
        int lane = t & 63, wv = t >> 6;
        int quad = lane >> 4, m15 = lane & 15;
        int strip = (blockIdx.x - 2500) * 4 + wv;      // [0,2500)
        int m0 = strip * 16;
        bf16x8 af[4];
        const float* arow = x + (size_t)(m0 + m15) * HID;
        #pragma unroll
        for (int ks = 0; ks < 4; ++ks) {
            float4 u = *(const float4*)(arow + ks * 32 + quad * 8);
            float4 v = *(const float4*)(arow + ks * 32 + quad * 8 + 4);
            bf16x8 f;
            f[0] = (short)f2bf(u.x); f[1] = (short)f2bf(u.y);
            f[2] = (short)f2bf(u.z); f[3] = (short)f2bf(u.w);
            f[4] = (short)f2bf(v.x); f[5] = (short)f2bf(v.y);
            f[6] = (short)f2bf(v.z); f[7] = (short)f2bf(v.w);
            af[ks] = f;
        }
        #pragma unroll
        for (int nt = 0; nt < 8; ++nt) {
            f32x4 acc = {0.f, 0.f, 0.f, 0.f};
            #pragma unroll
            for (int ks = 0; ks < 4; ++ks) {
                bf16x8 bfr = *(const bf16x8*)(&wlds[((nt * 4 + ks) * 64 + lane) * 8]);
                acc = __builtin_amdgcn_mfma_f32_16x16x32_bf16(af[ks], bfr, acc, 0, 0, 0);
            }
            #pragma unroll
            for (int r = 0; r < 4; ++r) {
                float zc = acc[r] * dinv[m0 + quad * 4 + r];
                int pk = __builtin_amdgcn_cvt_pk_fp8_f32(zc, zc, 0, false);
                z1[(size_t)(m0 + quad * 4 + r) * HID + nt * 16 + m15] = (u8)pk;
            }
        }
    }
}

// ---------------- k3: FUSED agg1 + gemm2.  Block = 16 nodes.  z1 -> h1(LDS) -> z2 ----
__launch_bounds__(256, 8)
__global__ void k_agg_gemm(const u8* __restrict__ zin, const float* __restrict__ dinv,
                           const int* __restrict__ rploc, const int* __restrict__ bsum,
                           const int* __restrict__ csr, const float* __restrict__ bias,
                           const u16* __restrict__ wswz2, u8* __restrict__ zout) {
    __shared__ int sboff[NBSUM];
    __shared__ int wsum[4];
    __shared__ u16 htile[16 * 136];   // +8 u16 row pad -> conflict-free ds_read_b128
    block_boff(bsum, sboff, wsum);

    int t = threadIdx.x;
    int lane = t & 63, wv = t >> 6;
    int q = lane >> 4, sub = lane & 15;
    int i = blockIdx.x * 16 + wv * 4 + q;                    // 2500*16 = 40000 exact
    float di = dinv[i];
    const u8* base = zin + (size_t)sub * 8;
    uint2 ps = *(const uint2*)(base + (size_t)i * HID);
    float a[8];
    {
        f32x2 t0 = __builtin_amdgcn_cvt_pk_f32_fp8((int)ps.x, false);
        f32x2 t1 = __builtin_amdgcn_cvt_pk_f32_fp8((int)ps.x, true);
        f32x2 t2 = __builtin_amdgcn_cvt_pk_f32_fp8((int)ps.y, false);
        f32x2 t3 = __builtin_amdgcn_cvt_pk_f32_fp8((int)ps.y, true);
        a[0] = t0[0]; a[1] = t0[1]; a[2] = t1[0]; a[3] = t1[1];
        a[4] = t2[0]; a[5] = t2[1]; a[6] = t3[0]; a[7] = t3[1];
    }
    int e  = rploc[i] + sboff[i >> 8];
    int e1 = rploc[i + 1] + sboff[(i + 1) >> 8];
    agg_gather(base, csr, e, e1, a);

    float4 b0 = *(const float4*)(bias + sub * 8);
    float4 b1v = *(const float4*)(bias + sub * 8 + 4);
    float r0 = fmaxf(di * a[0] + b0.x, 0.f),  r1 = fmaxf(di * a[1] + b0.y, 0.f);
    float r2 = fmaxf(di * a[2] + b0.z, 0.f),  r3 = fmaxf(di * a[3] + b0.w, 0.f);
    float r4 = fmaxf(di * a[4] + b1v.x, 0.f), r5 = fmaxf(di * a[5] + b1v.y, 0.f);
    float r6 = fmaxf(di * a[6] + b1v.z, 0.f), r7 = fmaxf(di * a[7] + b1v.w, 0.f);
    int nl = wv * 4 + q;
    uint4 o;
    o.x = (uint32_t)f2bf(r0) | ((uint32_t)f2bf(r1) << 16);
    o.y = (uint32_t)f2bf(r2) | ((uint32_t)f2bf(r3) << 16);
    o.z = (uint32_t)f2bf(r4) | ((uint32_t)f2bf(r5) << 16);
    o.w = (uint32_t)f2bf(r6) | ((uint32_t)f2bf(r7) << 16);
    *(uint4*)(&htile[nl * 136 + sub * 8]) = o;
    __syncthreads();

    // gemm phase: wave wv handles ntiles wv*2, wv*2+1
    int quad = q, m15 = sub;   // same decomposition
    bf16x8 af[4];
    #pragma unroll
    for (int ks = 0; ks < 4; ++ks)
        af[ks] = *(const bf16x8*)(&htile[m15 * 136 + ks * 32 + quad * 8]);
    int m0 = blockIdx.x * 16;
    #pragma unroll
    for (int n2 = 0; n2 < 2; ++n2) {
        int nt = wv * 2 + n2;
        f32x4 acc = {0.f, 0.f, 0.f, 0.f};
        #pragma unroll
        for (int ks = 0; ks < 4; ++ks) {
            bf16x8 bfr = *(const bf16x8*)(wswz2 + ((nt * 4 + ks) * 64 + lane) * 8);
            acc = __builtin_amdgcn_mfma_f32_16x16x32_bf16(af[ks], bfr, acc, 0, 0, 0);
        }
        #pragma unroll
        for (int r = 0; r < 4; ++r) {
            float zc = acc[r] * dinv[m0 + quad * 4 + r];
            int pk = __builtin_amdgcn_cvt_pk_fp8_f32(zc, zc, 0, false);
            zout[(size_t)(m0 + quad * 4 + r) * HID + nt * 16 + m15] = (u8)pk;
        }
    }
}

// ---------------- k4: FUSED agg2 + pooling.  h2 never hits HBM. ----------------
__launch_bounds__(256, 8)
__global__ void k_agg2pool(const u8* __restrict__ zin, const float* __restrict__ dinv,
                           const int* __restrict__ rploc, const int* __restrict__ bsum,
                           const int* __restrict__ csr, const float* __restrict__ bias,
                           const int* __restrict__ batch, float* __restrict__ pool) {
    __shared__ int sboff[NBSUM];
    __shared__ int wsum[4];
    __shared__ float hf[16 * 132];   // fp32 rows, +4 pad
    __shared__ int sbatch[16];
    block_boff(bsum, sboff, wsum);
    int t = threadIdx.x;
    int lane = t & 63, wv = t >> 6;
    int q = lane >> 4, sub = lane & 15;
    int i = blockIdx.x * 16 + wv * 4 + q;
    if (t < 16) sbatch[t] = batch[blockIdx.x * 16 + t];
    float di = dinv[i];
    const u8* base = zin + (size_t)sub * 8;
    uint2 ps = *(const uint2*)(base + (size_t)i * HID);
    float a[8];
    {
        f32x2 t0 = __builtin_amdgcn_cvt_pk_f32_fp8((int)ps.x, false);
        f32x2 t1 = __builtin_amdgcn_cvt_pk_f32_fp8((int)ps.x, true);
        f32x2 t2 = __builtin_amdgcn_cvt_pk_f32_fp8((int)ps.y, false);
        f32x2 t3 = __builtin_amdgcn_cvt_pk_f32_fp8((int)ps.y, true);
        a[0] = t0[0]; a[1] = t0[1]; a[2] = t1[0]; a[3] = t1[1];
        a[4] = t2[0]; a[5] = t2[1]; a[6] = t3[0]; a[7] = t3[1];
    }
    int e  = rploc[i] + sboff[i >> 8];
    int e1 = rploc[i + 1] + sboff[(i + 1) >> 8];
    agg_gather(base, csr, e, e1, a);

    float4 b0 = *(const float4*)(bias + sub * 8);
    float4 b1v = *(const float4*)(bias + sub * 8 + 4);
    int nl = wv * 4 + q;
    float* hrow = &hf[nl * 132 + sub * 8];
    float4 o0, o1;
    o0.x = fmaxf(di * a[0] + b0.x, 0.f);  o0.y = fmaxf(di * a[1] + b0.y, 0.f);
    o0.z = fmaxf(di * a[2] + b0.z, 0.f);  o0.w = fmaxf(di * a[3] + b0.w, 0.f);
    o1.x = fmaxf(di * a[4] + b1v.x, 0.f); o1.y = fmaxf(di * a[5] + b1v.y, 0.f);
    o1.z = fmaxf(di * a[6] + b1v.z, 0.f); o1.w = fmaxf(di * a[7] + b1v.w, 0.f);
    *(float4*)hrow = o0;
    *(float4*)(hrow + 4) = o1;
    __syncthreads();

    if (t < HID) {
        float s = 0.f;
        int gcur = sbatch[0];
        #pragma unroll
        for (int j = 0; j < 16; ++j) {
            int gj = sbatch[j];
            if (gj != gcur) {                       // segment boundary (rare)
                atomicAdd(&pool[gcur * HID + t], s);
                s = 0.f;
                gcur = gj;
            }
            s += hf[j * 132 + t];
        }
        atomicAdd(&pool[gcur * HID + t], s);
    }
}

// ---------------- k5: pool -> mean -> linear ----------------
__launch_bounds__(128)
__global__ void k_pool2(const float* __restrict__ pool, const int* __restrict__ batch,
                        const float* __restrict__ lin_w, const float* __restrict__ lin_b,
                        float* __restrict__ outp) {
    __shared__ float sh[HID];
    int g = blockIdx.x;
    int t = threadIdx.x;   // 128 threads, thread = feature
    int lo = 0, n = N_NODES;
    while (n > 0) { int half = n >> 1; int mid = lo + half;
        if (batch[mid] < g) { lo = mid + 1; n -= half + 1; } else n = half; }
    int hi = lo, n2 = N_NODES - lo;
    while (n2 > 0) { int half = n2 >> 1; int mid = hi + half;
        if (batch[mid] < g + 1) { hi = mid + 1; n2 -= half + 1; } else n2 = half; }
    float c = fmaxf((float)(hi - lo), 1.f);
    sh[t] = pool[g * HID + t] / c;
    __syncthreads();
    if (t < NCLASS) {
        float a = lin_b[t];
        #pragma unroll 8
        for (int f = 0; f < HID; ++f)
            a += sh[f] * lin_w[f * NCLASS + t];
        outp[g * NCLASS + t] = a;
    }
}

extern "C" void kernel_launch(void* const* d_in, const int* in_sizes, int n_in,
                              void* d_out, int out_size, void* d_ws, size_t ws_size,
                              hipStream_t stream) {
    const float* x    = (const float*)d_in[0];
    const int* eidx   = (const int*)d_in[1];
    const int* batch  = (const int*)d_in[2];
    const float* W1   = (const float*)d_in[3];
    const float* b1   = (const float*)d_in[4];
    const float* W2   = (const float*)d_in[5];
    const float* b2   = (const float*)d_in[6];
    const float* lw   = (const float*)d_in[7];
    const float* lb   = (const float*)d_in[8];
    float* out = (float*)d_out;

    char* ws = (char*)d_ws;
    int*   cnt     = (int*)(ws + 0);                 // 160000 B \ memset
    float* pool    = (float*)(ws + 160000);          // 32768 B  / [0,192768)
    int*   bsum    = (int*)(ws + 192768);            // 1024 B
    int*   rploc   = (int*)(ws + 193792);            // 160768 B (40192 ints)
    float* dinv    = (float*)(ws + 354560);          // 160000 B
    int*   csr     = (int*)(ws + 514560);            // 2560000 B
    u16*   wswz1   = (u16*)(ws + 3074560);           // 32768 B
    u16*   wswz2   = (u16*)(ws + 3107328);           // 32768 B
    u8*    bufZ1   = (u8*)(ws + 3140096);            // 5120000 B (fp8 z1)
    u8*    bufZ2   = (u8*)(ws + 8260096);            // 5120000 B (fp8 z2)  ~13.4 MB total

    const int* src = eidx;             // edge_index[0]
    const int* dst = eidx + N_EDGES;   // edge_index[1]

    hipMemsetAsync(d_ws, 0, 192768, stream);
    k_deg_wprep<<<2628, 256, 0, stream>>>(dst, cnt, W1, W2, wswz1, wswz2);
    k_scan1<<<157, 256, 0, stream>>>(cnt, dinv, rploc, bsum);
    k_fill_gemm1<<<3125, 256, 0, stream>>>(src, dst, rploc, bsum, cnt, csr,
                                           x, wswz1, dinv, bufZ1);       // csr + z1
    k_agg_gemm<<<2500, 256, 0, stream>>>(bufZ1, dinv, rploc, bsum, csr, b1,
                                         wswz2, bufZ2);                  // h1 in LDS -> z2
    k_agg2pool<<<2500, 256, 0, stream>>>(bufZ2, dinv, rploc, bsum, csr, b2,
                                         batch, pool);                   // h2 -> pool sums
    k_pool2<<<NGRAPH, 128, 0, stream>>>(pool, batch, lw, lb, out);
}